// Round 1
// baseline (318.569 us; speedup 1.0000x reference)
//
#include <hip/hip_runtime.h>

#define DEV __device__ __forceinline__

typedef __attribute__((ext_vector_type(8))) short short8;
typedef __attribute__((ext_vector_type(4))) float floatx4;
typedef __attribute__((ext_vector_type(4))) int i32x4;
typedef __attribute__((ext_vector_type(2))) long longx2;

DEV unsigned short f2bs(float x) {
    unsigned u = __float_as_uint(x);
    unsigned r = (u + 0x7fffu + ((u >> 16) & 1u)) >> 16;
    return (unsigned short)r;
}

// f32 -> OCP e4m3fn. Caller pre-clamps to [-448, 448]. Fallback: branchless, FTZ below 2^-6.
DEV unsigned char f2fp8(float x) {
#if __has_builtin(__builtin_amdgcn_cvt_pk_fp8_f32)
    int pk = __builtin_amdgcn_cvt_pk_fp8_f32(x, 0.f, 0, false);
    return (unsigned char)(pk & 0xff);
#else
    unsigned u = __float_as_uint(x);
    unsigned s = (u >> 24) & 0x80;
    unsigned a = u & 0x7fffffff;
    unsigned um = a + 0x7ffffu + ((a >> 20) & 1u);
    unsigned r = (a >= 0x3c800000u) ? ((um >> 20) - 0x3C0u) : 0u;
    return (unsigned char)(r | s);
#endif
}

DEV unsigned pack_fp8x4(float v0, float v1, float v2, float v3) {
#if __has_builtin(__builtin_amdgcn_cvt_pk_fp8_f32)
    unsigned pk = (unsigned)__builtin_amdgcn_cvt_pk_fp8_f32(v0, v1, 0, false);
    pk = (unsigned)__builtin_amdgcn_cvt_pk_fp8_f32(v2, v3, (int)pk, true);
    return pk;
#else
    return (unsigned)f2fp8(v0) | ((unsigned)f2fp8(v1) << 8) |
           ((unsigned)f2fp8(v2) << 16) | ((unsigned)f2fp8(v3) << 24);
#endif
}

DEV unsigned pack_i8x4(float v0, float v1, float v2, float v3) {
    unsigned b0 = (unsigned)((int)rintf(v0)) & 255u;
    unsigned b1 = (unsigned)((int)rintf(v1)) & 255u;
    unsigned b2 = (unsigned)((int)rintf(v2)) & 255u;
    unsigned b3 = (unsigned)((int)rintf(v3)) & 255u;
    return b0 | (b1 << 8) | (b2 << 16) | (b3 << 24);
}

// ---------------- merged pre-pass: setup (blocks 0..1024) + gn_stats (1025..1152) ----------------
// wp's k-columns get the pack4 permutation (col 16j+lc -> 4lc+j within each 64-block)
// to match o_t's permuted store layout in gemm_fp8_o.
__global__ void pre_kernel(const float* __restrict__ x,
                           const float* __restrict__ qw, const float* __restrict__ kw,
                           const float* __restrict__ vw, const float* __restrict__ pw,
                           const float* __restrict__ qb, const float* __restrict__ kb,
                           unsigned short* __restrict__ wqkb, unsigned short* __restrict__ wvb,
                           unsigned short* __restrict__ wpb,
                           float* __restrict__ biasqk, float* __restrict__ rowsum,
                           float* __restrict__ stats) {
    int b = blockIdx.x, tid = threadIdx.x;
    if (b < 768) {
        const float* src = (b < 256) ? qw : (b < 512) ? kw : vw;
        unsigned short* dst = (b < 256) ? wqkb : (b < 512) ? (wqkb + 262144) : wvb;
        int off = (b & 255) * 256 + tid;
        float4 v = ((const float4*)src)[off];
        ushort4 o;
        o.x = f2bs(v.x); o.y = f2bs(v.y); o.z = f2bs(v.z); o.w = f2bs(v.w);
        ((ushort4*)dst)[off] = o;
    } else if (b < 1024) {
        int off = (b - 768) * 256 + tid;
        int row = off >> 7, c4 = (off & 127) * 4;
        float4 v = ((const float4*)pw)[off];
        float vv[4] = {v.x, v.y, v.z, v.w};
#pragma unroll
        for (int e = 0; e < 4; ++e) {
            int c = c4 + e;
            int j = (c >> 4) & 3, lc = c & 15;
            int cp = (c & ~63) | (lc * 4 + j);
            wpb[row * 512 + cp] = f2bs(vv[e]);
        }
    } else if (b == 1024) {
        biasqk[tid]       = qb[tid];
        biasqk[256 + tid] = qb[256 + tid];
        biasqk[512 + tid] = kb[tid];
        biasqk[768 + tid] = kb[256 + tid];
        float4 z = {0.f, 0.f, 0.f, 0.f};
#pragma unroll
        for (int k = 0; k < 16; ++k) ((float4*)rowsum)[k * 256 + tid] = z;
    } else {
        int bg = b - 1025;  // 0..127
        const float4* p = (const float4*)(x + (size_t)bg * 65536);
        float s = 0.f, ss = 0.f;
        for (int i = tid; i < 16384; i += 256) {
            float4 v = p[i];
            s += v.x + v.y + v.z + v.w;
            ss += v.x * v.x + v.y * v.y + v.z * v.z + v.w * v.w;
        }
        for (int off = 32; off; off >>= 1) { s += __shfl_down(s, off); ss += __shfl_down(ss, off); }
        __shared__ float rs[4], rss[4];
        int wave = tid >> 6, lane = tid & 63;
        if (lane == 0) { rs[wave] = s; rss[wave] = ss; }
        __syncthreads();
        if (tid == 0) {
            float S = rs[0] + rs[1] + rs[2] + rs[3];
            float SS = rss[0] + rss[1] + rss[2] + rss[3];
            float mean = S * (1.f / 65536.f);
            float var = SS * (1.f / 65536.f) - mean * mean;
            stats[bg * 2] = mean;
            stats[bg * 2 + 1] = rsqrtf(var + 1e-5f);
        }
    }
}

// ------------- GN apply + transpose: x[b][c][p] fp32 -> h_t[b][p][c] bf16 -------------
__global__ void gn_apply_kernel(const float* __restrict__ x, const float* __restrict__ stats,
                                const float* __restrict__ gw, const float* __restrict__ gb,
                                unsigned short* __restrict__ ht) {
    __shared__ __align__(16) unsigned short t[64][72];
    int b = blockIdx.z, c0 = blockIdx.y * 64, p0 = blockIdx.x * 64;
    int tid = threadIdx.x;
    const float* xb = x + ((size_t)b * 512 + c0) * 4096 + p0;
#pragma unroll
    for (int pass = 0; pass < 4; ++pass) {
        int cl = pass * 16 + (tid >> 4);
        int pq = (tid & 15) * 4;
        float4 v = *(const float4*)(xb + (size_t)cl * 4096 + pq);
        int c = c0 + cl, g = c >> 4;
        float mean = stats[(b * 32 + g) * 2], rstd = stats[(b * 32 + g) * 2 + 1];
        float sw = gw[c] * rstd;
        float sb = gb[c] - mean * sw;
        t[pq + 0][cl] = f2bs(v.x * sw + sb);
        t[pq + 1][cl] = f2bs(v.y * sw + sb);
        t[pq + 2][cl] = f2bs(v.z * sw + sb);
        t[pq + 3][cl] = f2bs(v.w * sw + sb);
    }
    __syncthreads();
    unsigned short* hb = ht + ((size_t)b * 4096 + p0) * 512 + c0;
#pragma unroll
    for (int pass = 0; pass < 2; ++pass) {
        int pl = pass * 32 + (tid >> 3);
        int c8 = (tid & 7) * 8;
        *(uint4*)(hb + (size_t)pl * 512 + c8) = *(const uint4*)&t[pl][c8];
    }
}

// ---------------- merged qkv NT GEMM (K=512, bf16): blocks 0..1023 = q|k, 1024..1535 = v ----------------
// q|k: A=h_t[b], B=wqk, M=4096, N=1024 -> i8 pack4 split at 512 (scale QS, bias[n])
// v:   A=wv,     B=h_t[b], M=512, N=4096 -> fp8 e4m3 pack4 (bias[m])
__global__ void gemm_qkv(const unsigned short* __restrict__ h_t, long long sP,
                         const unsigned short* __restrict__ wqkb,
                         const unsigned short* __restrict__ wvb,
                         char* __restrict__ q_i8, char* __restrict__ k_i8,
                         char* __restrict__ v_f8,
                         const float* __restrict__ biasqk, const float* __restrict__ vb,
                         float qs) {
    __shared__ __align__(16) unsigned short lA[128 * 64];
    __shared__ __align__(16) unsigned short lB[128 * 64];
    const int tid = threadIdx.x;
    const int wave = tid >> 6, lane = tid & 63;
    const int flat = blockIdx.x;
    const bool isqk = flat < 1024;
    int m0, n0, bz;
    const unsigned short *Ab, *Bb;
    if (isqk) {
        m0 = ((flat >> 3) & 31) * 128;
        n0 = (flat & 7) * 128;
        bz = flat >> 8;
        Ab = h_t + (size_t)bz * sP;
        Bb = wqkb;
    } else {
        const int g = flat - 1024;
        m0 = ((g >> 5) & 3) * 128;
        n0 = (g & 31) * 128;
        bz = g >> 7;
        Ab = wvb;
        Bb = h_t + (size_t)bz * sP;
    }

    floatx4 acc[4][4];
#pragma unroll
    for (int i = 0; i < 4; i++)
#pragma unroll
        for (int j = 0; j < 4; j++) acc[i][j] = (floatx4){0.f, 0.f, 0.f, 0.f};

    const int wm = (wave >> 1) * 64, wn = (wave & 1) * 64;
    const int quad = lane >> 4;
    const int lc = lane & 15;
    const int lc7 = lc & 7;

    for (int kt = 0; kt < 8; ++kt) {
        const int kbase = kt * 64;
#pragma unroll
        for (int c = 0; c < 4; ++c) {
            int d = c * 256 + tid;
            int r = d >> 3;
            int kc = (d & 7) ^ (r & 7);
            const unsigned short* ga = Ab + (size_t)(m0 + r) * 512 + kbase + kc * 8;
            const unsigned short* gb = Bb + (size_t)(n0 + r) * 512 + kbase + kc * 8;
            __builtin_amdgcn_global_load_lds(
                (const __attribute__((address_space(1))) void*)ga,
                (__attribute__((address_space(3))) void*)&lA[(size_t)(c * 256 + wave * 64) * 8], 16, 0, 0);
            __builtin_amdgcn_global_load_lds(
                (const __attribute__((address_space(1))) void*)gb,
                (__attribute__((address_space(3))) void*)&lB[(size_t)(c * 256 + wave * 64) * 8], 16, 0, 0);
        }
        __syncthreads();
#pragma unroll
        for (int kk = 0; kk < 2; ++kk) {
            const int swz = ((kk * 4 + quad) ^ lc7) * 8;
            short8 af[4], bf[4];
#pragma unroll
            for (int i = 0; i < 4; i++)
                af[i] = *(const short8*)&lA[(size_t)(wm + i * 16 + lc) * 64 + swz];
#pragma unroll
            for (int j = 0; j < 4; j++)
                bf[j] = *(const short8*)&lB[(size_t)(wn + j * 16 + lc) * 64 + swz];
#pragma unroll
            for (int i = 0; i < 4; i++)
#pragma unroll
                for (int j = 0; j < 4; j++)
                    acc[i][j] = __builtin_amdgcn_mfma_f32_16x16x32_bf16(af[i], bf[j], acc[i][j], 0, 0, 0);
        }
        __syncthreads();
    }

    const int rowb = quad * 4;
    if (isqk) {
#pragma unroll
        for (int i = 0; i < 4; i++) {
#pragma unroll
            for (int r = 0; r < 4; r++) {
                const int m = m0 + wm + i * 16 + rowb + r;
                float q[4];
#pragma unroll
                for (int j = 0; j < 4; j++) {
                    const int n = n0 + wn + j * 16 + lc;
                    q[j] = fminf(fmaxf((acc[i][j][r] + biasqk[n]) * qs, -127.f), 127.f);
                }
                const int col64 = n0 + wn;
                char* outp = (col64 < 512) ? q_i8 : k_i8;
                size_t idx = (size_t)bz * sP + (size_t)m * 512 +
                             (col64 - ((col64 < 512) ? 0 : 512)) + lc * 4;
                *(unsigned*)(outp + idx) = pack_i8x4(q[0], q[1], q[2], q[3]);
            }
        }
    } else {
#pragma unroll
        for (int i = 0; i < 4; i++) {
#pragma unroll
            for (int r = 0; r < 4; r++) {
                const int m = m0 + wm + i * 16 + rowb + r;
                const float bm = vb[m];
                float q[4];
#pragma unroll
                for (int j = 0; j < 4; j++)
                    q[j] = fminf(fmaxf(acc[i][j][r] + bm, -448.f), 448.f);
                size_t idx = (size_t)bz * sP + (size_t)m * 4096 + n0 + wn + lc * 4;
                *(unsigned*)(v_f8 + idx) = pack_fp8x4(q[0], q[1], q[2], q[3]);
            }
        }
    }
}

// ---------------- NT GEMM, bf16, fp32-out epilogue (proj): y = A.B^T + bias[m] + resid ----------------
__global__ void gemm_proj(const unsigned short* __restrict__ A,
                          const unsigned short* __restrict__ B, long long sBb,
                          float* __restrict__ Cv, long long sCb,
                          const float* __restrict__ bias,
                          const float* __restrict__ resid, long long sRb,
                          int M, int N, int K) {
    __shared__ __align__(16) unsigned short lA[128 * 64];
    __shared__ __align__(16) unsigned short lB[128 * 64];
    const int tid = threadIdx.x;
    const int wave = tid >> 6, lane = tid & 63;
    const int m0 = blockIdx.y * 128, n0 = blockIdx.x * 128, bz = blockIdx.z;
    const unsigned short* Ab = A;
    const unsigned short* Bb = B + (size_t)bz * sBb;

    floatx4 acc[4][4];
#pragma unroll
    for (int i = 0; i < 4; i++)
#pragma unroll
        for (int j = 0; j < 4; j++) acc[i][j] = (floatx4){0.f, 0.f, 0.f, 0.f};

    const int wm = (wave >> 1) * 64, wn = (wave & 1) * 64;
    const int quad = lane >> 4;
    const int lc = lane & 15;
    const int lc7 = lc & 7;

    const int nk = K >> 6;
    for (int kt = 0; kt < nk; ++kt) {
        const int kbase = kt * 64;
#pragma unroll
        for (int c = 0; c < 4; ++c) {
            int d = c * 256 + tid;
            int r = d >> 3;
            int kc = (d & 7) ^ (r & 7);
            const unsigned short* ga = Ab + (size_t)(m0 + r) * K + kbase + kc * 8;
            const unsigned short* gb = Bb + (size_t)(n0 + r) * K + kbase + kc * 8;
            __builtin_amdgcn_global_load_lds(
                (const __attribute__((address_space(1))) void*)ga,
                (__attribute__((address_space(3))) void*)&lA[(size_t)(c * 256 + wave * 64) * 8], 16, 0, 0);
            __builtin_amdgcn_global_load_lds(
                (const __attribute__((address_space(1))) void*)gb,
                (__attribute__((address_space(3))) void*)&lB[(size_t)(c * 256 + wave * 64) * 8], 16, 0, 0);
        }
        __syncthreads();
#pragma unroll
        for (int kk = 0; kk < 2; ++kk) {
            const int swz = ((kk * 4 + quad) ^ lc7) * 8;
            short8 af[4], bf[4];
#pragma unroll
            for (int i = 0; i < 4; i++)
                af[i] = *(const short8*)&lA[(size_t)(wm + i * 16 + lc) * 64 + swz];
#pragma unroll
            for (int j = 0; j < 4; j++)
                bf[j] = *(const short8*)&lB[(size_t)(wn + j * 16 + lc) * 64 + swz];
#pragma unroll
            for (int i = 0; i < 4; i++)
#pragma unroll
                for (int j = 0; j < 4; j++)
                    acc[i][j] = __builtin_amdgcn_mfma_f32_16x16x32_bf16(af[i], bf[j], acc[i][j], 0, 0, 0);
        }
        __syncthreads();
    }

    const int rowb = quad * 4;
#pragma unroll
    for (int i = 0; i < 4; i++) {
#pragma unroll
        for (int r = 0; r < 4; r++) {
            const int m = m0 + wm + i * 16 + rowb + r;
            const float bm = bias[m];
#pragma unroll
            for (int j = 0; j < 4; j++) {
                const int n = n0 + wn + j * 16 + lc;
                size_t idx = (size_t)bz * sCb + (size_t)m * N + n;
                Cv[idx] = acc[i][j][r] + bm + resid[(size_t)bz * sRb + (size_t)m * N + n];
            }
        }
    }
}

// ---------------- i8 NT GEMM: P = e4m3(0.25*exp(qk*scale)), pack4, shuffle+atomic rowsum ----------------
// 256x256 tile, 8 waves (2M x 4N of 128x64), BK=128, double-buffered LDS (128 KB),
// minimal 2-phase pipeline: issue next-tile global_load_lds BEFORE ds_read+MFMA of current
// tile, single __syncthreads (vmcnt drain) per K-tile. s_setprio(1) around MFMA cluster.
__global__ __launch_bounds__(512) void gemm_i8_exp(const char* __restrict__ A, long long sAb,
                            const char* __restrict__ B, long long sBb,
                            char* __restrict__ Cv, long long sCb,
                            float* __restrict__ rowsum,
                            int M, int N, int K, float scale2) {
    __shared__ __align__(16) char lA[2][256 * 128];
    __shared__ __align__(16) char lB[2][256 * 128];
    const int tid = threadIdx.x;
    const int wave = tid >> 6, lane = tid & 63;
    const int m0 = blockIdx.y * 256, n0 = blockIdx.x * 256, bz = blockIdx.z;
    const char* Ab = A + (size_t)bz * sAb;
    const char* Bb = B + (size_t)bz * sBb;

    i32x4 acc[8][4];
#pragma unroll
    for (int i = 0; i < 8; i++)
#pragma unroll
        for (int j = 0; j < 4; j++) acc[i][j] = (i32x4){0, 0, 0, 0};

    const int wm = (wave >> 2) * 128, wn = (wave & 3) * 64;
    const int quad = lane >> 4;
    const int lc = lane & 15;
    const int lc7 = lc & 7;

    // stage one 256x128 A-tile + 256x128 B-tile (64 KB) into buf; 8 loads/thread
    auto stage = [&](char* dA, char* dB, int kbase) {
#pragma unroll
        for (int c = 0; c < 4; ++c) {
            int d = c * 512 + tid;
            int r = d >> 3;
            int s = ((d & 7) ^ (r & 7)) * 16;
            const char* ga = Ab + (size_t)(m0 + r) * K + kbase + s;
            const char* gb = Bb + (size_t)(n0 + r) * K + kbase + s;
            __builtin_amdgcn_global_load_lds(
                (const __attribute__((address_space(1))) void*)ga,
                (__attribute__((address_space(3))) void*)(dA + (size_t)(c * 512 + wave * 64) * 16), 16, 0, 0);
            __builtin_amdgcn_global_load_lds(
                (const __attribute__((address_space(1))) void*)gb,
                (__attribute__((address_space(3))) void*)(dB + (size_t)(c * 512 + wave * 64) * 16), 16, 0, 0);
        }
    };

    const int nk = K >> 7;  // 4
    stage(lA[0], lB[0], 0);
    __syncthreads();
    int buf = 0;
    for (int kt = 0; kt < nk; ++kt) {
        if (kt + 1 < nk) stage(lA[buf ^ 1], lB[buf ^ 1], (kt + 1) << 7);
        const char* pa = lA[buf];
        const char* pb = lB[buf];
#pragma unroll
        for (int kk = 0; kk < 2; ++kk) {
            i32x4 bf[4];
#pragma unroll
            for (int fj = 0; fj < 4; ++fj)
                bf[fj] = *(const i32x4*)&pb[(size_t)(wn + fj * 16 + lc) * 128 +
                                            (((kk * 4 + quad) ^ lc7) << 4)];
            __builtin_amdgcn_s_setprio(1);
#pragma unroll
            for (int fi = 0; fi < 8; ++fi) {
                i32x4 a = *(const i32x4*)&pa[(size_t)(wm + fi * 16 + lc) * 128 +
                                             (((kk * 4 + quad) ^ lc7) << 4)];
#pragma unroll
                for (int fj = 0; fj < 4; ++fj)
                    acc[fi][fj] = __builtin_amdgcn_mfma_i32_16x16x64_i8(a, bf[fj], acc[fi][fj], 0, 0, 0);
            }
            __builtin_amdgcn_s_setprio(0);
        }
        __syncthreads();  // drains vmcnt(0): next tile resident; lds[buf] free to overwrite
        buf ^= 1;
    }

    const int rowb = quad * 4;
#pragma unroll
    for (int fi = 0; fi < 8; ++fi) {
#pragma unroll
        for (int r = 0; r < 4; ++r) {
            const int m = m0 + wm + fi * 16 + rowb + r;
            float e[4];
            float rsacc = 0.f;
#pragma unroll
            for (int fj = 0; fj < 4; ++fj) {
                e[fj] = fminf(exp2f(fmaf((float)acc[fi][fj][r], scale2, -2.0f)), 448.f);
                rsacc += e[fj];
            }
            size_t oidx = (size_t)bz * sCb + (size_t)m * N + n0 + wn + lc * 4;
            *(unsigned*)(Cv + oidx) = pack_fp8x4(e[0], e[1], e[2], e[3]);
            rsacc += __shfl_xor(rsacc, 1);
            rsacc += __shfl_xor(rsacc, 2);
            rsacc += __shfl_xor(rsacc, 4);
            rsacc += __shfl_xor(rsacc, 8);
            if (lc == 0) atomicAdd(&rowsum[(size_t)bz * M + m], rsacc);
        }
    }
}

// ---------------- fp8 NT GEMM: O_t[q][d] = (sum_k P[q][k]*V[d][k]) / rowsum[q] ----------------
// bf16 out in pack4-permuted d layout (consumer proj uses permuted wp). XCD-swizzled.
__global__ void gemm_fp8_o(const char* __restrict__ A, long long sAb,
                           const char* __restrict__ B, long long sBb,
                           unsigned short* __restrict__ Cv, long long sCb,
                           const float* __restrict__ rowsum,
                           int M, int N, int K) {
    __shared__ __align__(16) char lA[128 * 128];
    __shared__ __align__(16) char lB[128 * 128];
    const int tid = threadIdx.x;
    const int wave = tid >> 6, lane = tid & 63;
    int flat = blockIdx.x;
    int xcd = flat & 7, idx = flat >> 3;
    int nt = idx & 3, si = idx >> 2;
    int stripe = xcd * 16 + si;
    const int m0 = (stripe & 31) * 128;
    const int n0 = nt * 128;
    const int bz = stripe >> 5;
    const char* Ab = A + (size_t)bz * sAb;
    const char* Bb = B + (size_t)bz * sBb;

    floatx4 acc[4][4];
#pragma unroll
    for (int i = 0; i < 4; i++)
#pragma unroll
        for (int j = 0; j < 4; j++) acc[i][j] = (floatx4){0.f, 0.f, 0.f, 0.f};

    const int wm = (wave >> 1) * 64, wn = (wave & 1) * 64;
    const int quad = lane >> 4;
    const int lc = lane & 15;
    const int lc7 = lc & 7;
    const int half = quad & 1;

    const int nk = K >> 7;
    for (int kt = 0; kt < nk; ++kt) {
        const int kbase = kt * 128;
#pragma unroll
        for (int c = 0; c < 4; ++c) {
            int d = c * 256 + tid;
            int r = d >> 3;
            int kc = (d & 7) ^ (r & 7);
            const char* ga = Ab + (size_t)(m0 + r) * K + kbase + kc * 16;
            const char* gb = Bb + (size_t)(n0 + r) * K + kbase + kc * 16;
            __builtin_amdgcn_global_load_lds(
                (const __attribute__((address_space(1))) void*)ga,
                (__attribute__((address_space(3))) void*)&lA[(size_t)(c * 256 + wave * 64) * 16], 16, 0, 0);
            __builtin_amdgcn_global_load_lds(
                (const __attribute__((address_space(1))) void*)gb,
                (__attribute__((address_space(3))) void*)&lB[(size_t)(c * 256 + wave * 64) * 16], 16, 0, 0);
        }
        __syncthreads();
#pragma unroll
        for (int t = 0; t < 4; ++t) {
            const int swz = ((2 * t + (quad >> 1)) ^ lc7) * 16;
            long a8[4], b8[4];
#pragma unroll
            for (int i = 0; i < 4; i++) {
                longx2 v = *(const longx2*)&lA[(size_t)(wm + i * 16 + lc) * 128 + swz];
                a8[i] = v[half];
            }
#pragma unroll
            for (int j = 0; j < 4; j++) {
                longx2 v = *(const longx2*)&lB[(size_t)(wn + j * 16 + lc) * 128 + swz];
                b8[j] = v[half];
            }
#pragma unroll
            for (int i = 0; i < 4; i++)
#pragma unroll
                for (int j = 0; j < 4; j++)
                    acc[i][j] = __builtin_amdgcn_mfma_f32_16x16x32_fp8_fp8(a8[i], b8[j], acc[i][j], 0, 0, 0);
        }
        __syncthreads();
    }

    const int rowb = quad * 4;
#pragma unroll
    for (int i = 0; i < 4; i++) {
#pragma unroll
        for (int r = 0; r < 4; r++) {
            const int m = m0 + wm + i * 16 + rowb + r;
            const float pscale = 1.f / rowsum[(size_t)bz * M + m];
            unsigned short h[4];
#pragma unroll
            for (int j = 0; j < 4; j++) h[j] = f2bs(acc[i][j][r] * pscale);
            uint2 u;
            u.x = (unsigned)h[0] | ((unsigned)h[1] << 16);
            u.y = (unsigned)h[2] | ((unsigned)h[3] << 16);
            *(uint2*)&Cv[(size_t)bz * sCb + (size_t)m * N + n0 + wn + lc * 4] = u;
        }
    }
}

extern "C" void kernel_launch(void* const* d_in, const int* in_sizes, int n_in,
                              void* d_out, int out_size, void* d_ws, size_t ws_size,
                              hipStream_t stream) {
    (void)in_sizes; (void)n_in; (void)out_size; (void)ws_size;
    const float* x   = (const float*)d_in[0];
    const float* gnw = (const float*)d_in[1];
    const float* gnb = (const float*)d_in[2];
    const float* qw  = (const float*)d_in[3];
    const float* qb  = (const float*)d_in[4];
    const float* kw  = (const float*)d_in[5];
    const float* kb  = (const float*)d_in[6];
    const float* vw  = (const float*)d_in[7];
    const float* vb  = (const float*)d_in[8];
    const float* pw  = (const float*)d_in[9];
    const float* pb  = (const float*)d_in[10];
    float* out = (float*)d_out;

    char* ws = (char*)d_ws;
    unsigned short* h_t = (unsigned short*)(ws);
    unsigned short* o_t = h_t;  // alias: h_t dead after qkv GEMM
    char* q_i8 = (char*)(ws + (16ull << 20));
    char* k_i8 = (char*)(ws + (32ull << 20));
    char* v_f8 = (char*)(ws + (48ull << 20));
    unsigned short* wqkb = (unsigned short*)(ws + (64ull << 20));  // [qw;kw] 1024x512
    unsigned short* wvb = (unsigned short*)(ws + (65ull << 20));
    unsigned short* wpb = wvb + 262144;  // pack4-permuted k-cols
    float* stats  = (float*)(ws + (66ull << 20));
    float* rowsum = (float*)(ws + (66ull << 20) + 65536);
    float* biasqk = (float*)(ws + (66ull << 20) + 131072);
    char* p_f8 = (char*)(ws + (67ull << 20));

    const long long sP  = 2097152;   // 4096*512 elements per batch
    const long long sS  = 16777216;  // 4096*4096 bytes per batch (fp8 P)
    const float QS = 16.f;
    const float SC = 0.044194173824159216f / (QS * QS);
    const float LOG2E = 1.4426950408889634f;

    // setup + gn_stats merged
    pre_kernel<<<1153, 256, 0, stream>>>(x, qw, kw, vw, pw, qb, kb, wqkb, wvb, wpb,
                                         biasqk, rowsum, stats);
    gn_apply_kernel<<<dim3(64, 8, 4), 256, 0, stream>>>(x, stats, gnw, gnb, h_t);
    // merged q|k (1024 blocks) + v (512 blocks)
    gemm_qkv<<<1536, 256, 0, stream>>>(h_t, sP, wqkb, wvb, q_i8, k_i8, v_f8, biasqk, vb, QS);
    // P[q][k] = e4m3(0.25*exp(qk*SC)) pack4, shuffle+atomic rowsums
    // 256^2 tile, 8 waves, double-buffered 2-phase pipeline
    gemm_i8_exp<<<dim3(16, 16, 4), 512, 0, stream>>>(q_i8, sP, k_i8, sP, p_f8, sS, rowsum,
                                                     4096, 4096, 512, SC * LOG2E);
    // O_t[q][d] = (P . v^T)/rowsum: fp8 MFMA, pack4-permuted bf16 out, XCD-swizzled
    gemm_fp8_o<<<dim3(512, 1, 1), 256, 0, stream>>>(p_f8, sS, v_f8, sP, o_t, sP, rowsum,
                                                    4096, 512, 4096);
    // y = x + wp~ . O_t^T + pb: M=512(o), N=4096(p), K=512(d, permutation cancels)
    gemm_proj<<<dim3(32, 4, 4), 256, 0, stream>>>(wpb, o_t, sP, out, sP, pb, x, sP,
                                                  512, 4096, 512);
}

// Round 2
// 313.572 us; speedup vs baseline: 1.0159x; 1.0159x over previous
//
#include <hip/hip_runtime.h>

#define DEV __device__ __forceinline__

typedef __attribute__((ext_vector_type(8))) short short8;
typedef __attribute__((ext_vector_type(4))) float floatx4;
typedef __attribute__((ext_vector_type(4))) int i32x4;
typedef __attribute__((ext_vector_type(2))) long longx2;

DEV unsigned short f2bs(float x) {
    unsigned u = __float_as_uint(x);
    unsigned r = (u + 0x7fffu + ((u >> 16) & 1u)) >> 16;
    return (unsigned short)r;
}

// f32 -> OCP e4m3fn. Caller pre-clamps to [-448, 448]. Fallback: branchless, FTZ below 2^-6.
DEV unsigned char f2fp8(float x) {
#if __has_builtin(__builtin_amdgcn_cvt_pk_fp8_f32)
    int pk = __builtin_amdgcn_cvt_pk_fp8_f32(x, 0.f, 0, false);
    return (unsigned char)(pk & 0xff);
#else
    unsigned u = __float_as_uint(x);
    unsigned s = (u >> 24) & 0x80;
    unsigned a = u & 0x7fffffff;
    unsigned um = a + 0x7ffffu + ((a >> 20) & 1u);
    unsigned r = (a >= 0x3c800000u) ? ((um >> 20) - 0x3C0u) : 0u;
    return (unsigned char)(r | s);
#endif
}

DEV unsigned pack_fp8x4(float v0, float v1, float v2, float v3) {
#if __has_builtin(__builtin_amdgcn_cvt_pk_fp8_f32)
    unsigned pk = (unsigned)__builtin_amdgcn_cvt_pk_fp8_f32(v0, v1, 0, false);
    pk = (unsigned)__builtin_amdgcn_cvt_pk_fp8_f32(v2, v3, (int)pk, true);
    return pk;
#else
    return (unsigned)f2fp8(v0) | ((unsigned)f2fp8(v1) << 8) |
           ((unsigned)f2fp8(v2) << 16) | ((unsigned)f2fp8(v3) << 24);
#endif
}

DEV unsigned pack_i8x4(float v0, float v1, float v2, float v3) {
    unsigned b0 = (unsigned)((int)rintf(v0)) & 255u;
    unsigned b1 = (unsigned)((int)rintf(v1)) & 255u;
    unsigned b2 = (unsigned)((int)rintf(v2)) & 255u;
    unsigned b3 = (unsigned)((int)rintf(v3)) & 255u;
    return b0 | (b1 << 8) | (b2 << 16) | (b3 << 24);
}

DEV void syncfull() {
    asm volatile("s_waitcnt vmcnt(0) lgkmcnt(0)" ::: "memory");
    __builtin_amdgcn_sched_barrier(0);
    __builtin_amdgcn_s_barrier();
    __builtin_amdgcn_sched_barrier(0);
}

// ---------------- merged pre-pass: setup (blocks 0..1024) + gn_stats (1025..1152) ----------------
// wp's k-columns get the pack4 permutation (col 16j+lc -> 4lc+j within each 64-block)
// to match o_un's permuted store layout in attn_fused.
__global__ void pre_kernel(const float* __restrict__ x,
                           const float* __restrict__ qw, const float* __restrict__ kw,
                           const float* __restrict__ vw, const float* __restrict__ pw,
                           const float* __restrict__ qb, const float* __restrict__ kb,
                           unsigned short* __restrict__ wqkb, unsigned short* __restrict__ wvb,
                           unsigned short* __restrict__ wpb,
                           float* __restrict__ biasqk,
                           float* __restrict__ stats) {
    int b = blockIdx.x, tid = threadIdx.x;
    if (b < 768) {
        const float* src = (b < 256) ? qw : (b < 512) ? kw : vw;
        unsigned short* dst = (b < 256) ? wqkb : (b < 512) ? (wqkb + 262144) : wvb;
        int off = (b & 255) * 256 + tid;
        float4 v = ((const float4*)src)[off];
        ushort4 o;
        o.x = f2bs(v.x); o.y = f2bs(v.y); o.z = f2bs(v.z); o.w = f2bs(v.w);
        ((ushort4*)dst)[off] = o;
    } else if (b < 1024) {
        int off = (b - 768) * 256 + tid;
        int row = off >> 7, c4 = (off & 127) * 4;
        float4 v = ((const float4*)pw)[off];
        float vv[4] = {v.x, v.y, v.z, v.w};
#pragma unroll
        for (int e = 0; e < 4; ++e) {
            int c = c4 + e;
            int j = (c >> 4) & 3, lc = c & 15;
            int cp = (c & ~63) | (lc * 4 + j);
            wpb[row * 512 + cp] = f2bs(vv[e]);
        }
    } else if (b == 1024) {
        biasqk[tid]       = qb[tid];
        biasqk[256 + tid] = qb[256 + tid];
        biasqk[512 + tid] = kb[tid];
        biasqk[768 + tid] = kb[256 + tid];
    } else {
        int bg = b - 1025;  // 0..127
        const float4* p = (const float4*)(x + (size_t)bg * 65536);
        float s = 0.f, ss = 0.f;
        for (int i = tid; i < 16384; i += 256) {
            float4 v = p[i];
            s += v.x + v.y + v.z + v.w;
            ss += v.x * v.x + v.y * v.y + v.z * v.z + v.w * v.w;
        }
        for (int off = 32; off; off >>= 1) { s += __shfl_down(s, off); ss += __shfl_down(ss, off); }
        __shared__ float rs[4], rss[4];
        int wave = tid >> 6, lane = tid & 63;
        if (lane == 0) { rs[wave] = s; rss[wave] = ss; }
        __syncthreads();
        if (tid == 0) {
            float S = rs[0] + rs[1] + rs[2] + rs[3];
            float SS = rss[0] + rss[1] + rss[2] + rss[3];
            float mean = S * (1.f / 65536.f);
            float var = SS * (1.f / 65536.f) - mean * mean;
            stats[bg * 2] = mean;
            stats[bg * 2 + 1] = rsqrtf(var + 1e-5f);
        }
    }
}

// ------------- GN apply + transpose: x[b][c][p] fp32 -> h_t[b][p][c] bf16 -------------
__global__ void gn_apply_kernel(const float* __restrict__ x, const float* __restrict__ stats,
                                const float* __restrict__ gw, const float* __restrict__ gb,
                                unsigned short* __restrict__ ht) {
    __shared__ __align__(16) unsigned short t[64][72];
    int b = blockIdx.z, c0 = blockIdx.y * 64, p0 = blockIdx.x * 64;
    int tid = threadIdx.x;
    const float* xb = x + ((size_t)b * 512 + c0) * 4096 + p0;
#pragma unroll
    for (int pass = 0; pass < 4; ++pass) {
        int cl = pass * 16 + (tid >> 4);
        int pq = (tid & 15) * 4;
        float4 v = *(const float4*)(xb + (size_t)cl * 4096 + pq);
        int c = c0 + cl, g = c >> 4;
        float mean = stats[(b * 32 + g) * 2], rstd = stats[(b * 32 + g) * 2 + 1];
        float sw = gw[c] * rstd;
        float sb = gb[c] - mean * sw;
        t[pq + 0][cl] = f2bs(v.x * sw + sb);
        t[pq + 1][cl] = f2bs(v.y * sw + sb);
        t[pq + 2][cl] = f2bs(v.z * sw + sb);
        t[pq + 3][cl] = f2bs(v.w * sw + sb);
    }
    __syncthreads();
    unsigned short* hb = ht + ((size_t)b * 4096 + p0) * 512 + c0;
#pragma unroll
    for (int pass = 0; pass < 2; ++pass) {
        int pl = pass * 32 + (tid >> 3);
        int c8 = (tid & 7) * 8;
        *(uint4*)(hb + (size_t)pl * 512 + c8) = *(const uint4*)&t[pl][c8];
    }
}

// ---------------- merged qkv NT GEMM (K=512, bf16): blocks 0..1023 = q|k, 1024..1535 = v ----------------
// q|k: A=h_t[b], B=wqk, M=4096, N=1024 -> i8 pack4 split at 512 (scale QS, bias[n])
// v:   A=wv,     B=h_t[b], M=512, N=4096 -> fp8 e4m3 pack4 (bias[m])
__global__ void gemm_qkv(const unsigned short* __restrict__ h_t, long long sP,
                         const unsigned short* __restrict__ wqkb,
                         const unsigned short* __restrict__ wvb,
                         char* __restrict__ q_i8, char* __restrict__ k_i8,
                         char* __restrict__ v_f8,
                         const float* __restrict__ biasqk, const float* __restrict__ vb,
                         float qs) {
    __shared__ __align__(16) unsigned short lA[128 * 64];
    __shared__ __align__(16) unsigned short lB[128 * 64];
    const int tid = threadIdx.x;
    const int wave = tid >> 6, lane = tid & 63;
    const int flat = blockIdx.x;
    const bool isqk = flat < 1024;
    int m0, n0, bz;
    const unsigned short *Ab, *Bb;
    if (isqk) {
        m0 = ((flat >> 3) & 31) * 128;
        n0 = (flat & 7) * 128;
        bz = flat >> 8;
        Ab = h_t + (size_t)bz * sP;
        Bb = wqkb;
    } else {
        const int g = flat - 1024;
        m0 = ((g >> 5) & 3) * 128;
        n0 = (g & 31) * 128;
        bz = g >> 7;
        Ab = wvb;
        Bb = h_t + (size_t)bz * sP;
    }

    floatx4 acc[4][4];
#pragma unroll
    for (int i = 0; i < 4; i++)
#pragma unroll
        for (int j = 0; j < 4; j++) acc[i][j] = (floatx4){0.f, 0.f, 0.f, 0.f};

    const int wm = (wave >> 1) * 64, wn = (wave & 1) * 64;
    const int quad = lane >> 4;
    const int lc = lane & 15;
    const int lc7 = lc & 7;

    for (int kt = 0; kt < 8; ++kt) {
        const int kbase = kt * 64;
#pragma unroll
        for (int c = 0; c < 4; ++c) {
            int d = c * 256 + tid;
            int r = d >> 3;
            int kc = (d & 7) ^ (r & 7);
            const unsigned short* ga = Ab + (size_t)(m0 + r) * 512 + kbase + kc * 8;
            const unsigned short* gb = Bb + (size_t)(n0 + r) * 512 + kbase + kc * 8;
            __builtin_amdgcn_global_load_lds(
                (const __attribute__((address_space(1))) void*)ga,
                (__attribute__((address_space(3))) void*)&lA[(size_t)(c * 256 + wave * 64) * 8], 16, 0, 0);
            __builtin_amdgcn_global_load_lds(
                (const __attribute__((address_space(1))) void*)gb,
                (__attribute__((address_space(3))) void*)&lB[(size_t)(c * 256 + wave * 64) * 8], 16, 0, 0);
        }
        __syncthreads();
#pragma unroll
        for (int kk = 0; kk < 2; ++kk) {
            const int swz = ((kk * 4 + quad) ^ lc7) * 8;
            short8 af[4], bf[4];
#pragma unroll
            for (int i = 0; i < 4; i++)
                af[i] = *(const short8*)&lA[(size_t)(wm + i * 16 + lc) * 64 + swz];
#pragma unroll
            for (int j = 0; j < 4; j++)
                bf[j] = *(const short8*)&lB[(size_t)(wn + j * 16 + lc) * 64 + swz];
#pragma unroll
            for (int i = 0; i < 4; i++)
#pragma unroll
                for (int j = 0; j < 4; j++)
                    acc[i][j] = __builtin_amdgcn_mfma_f32_16x16x32_bf16(af[i], bf[j], acc[i][j], 0, 0, 0);
        }
        __syncthreads();
    }

    const int rowb = quad * 4;
    if (isqk) {
#pragma unroll
        for (int i = 0; i < 4; i++) {
#pragma unroll
            for (int r = 0; r < 4; r++) {
                const int m = m0 + wm + i * 16 + rowb + r;
                float q[4];
#pragma unroll
                for (int j = 0; j < 4; j++) {
                    const int n = n0 + wn + j * 16 + lc;
                    q[j] = fminf(fmaxf((acc[i][j][r] + biasqk[n]) * qs, -127.f), 127.f);
                }
                const int col64 = n0 + wn;
                char* outp = (col64 < 512) ? q_i8 : k_i8;
                size_t idx = (size_t)bz * sP + (size_t)m * 512 +
                             (col64 - ((col64 < 512) ? 0 : 512)) + lc * 4;
                *(unsigned*)(outp + idx) = pack_i8x4(q[0], q[1], q[2], q[3]);
            }
        }
    } else {
#pragma unroll
        for (int i = 0; i < 4; i++) {
#pragma unroll
            for (int r = 0; r < 4; r++) {
                const int m = m0 + wm + i * 16 + rowb + r;
                const float bm = vb[m];
                float q[4];
#pragma unroll
                for (int j = 0; j < 4; j++)
                    q[j] = fminf(fmaxf(acc[i][j][r] + bm, -448.f), 448.f);
                size_t idx = (size_t)bz * sP + (size_t)m * 4096 + n0 + wn + lc * 4;
                *(unsigned*)(v_f8 + idx) = pack_fp8x4(q[0], q[1], q[2], q[3]);
            }
        }
    }
}

// ---------------- fused attention: S^T = K.Q^T (i8) -> exp -> P (LDS, fp8, pack4-perm)
//                                   -> O_un += P.V^T (fp8), per-q rowsum partials ----------------
// Grid: 256 blocks = 8 xcd-groups (bz*2+split) x 32 q-tiles. 512 thr (8 waves). 1 block/CU.
// LDS: Q 64K + K 32K + V 32K + P 8K = 136K. kv-split: each block does kv in [split*2048, +2048).
// Normalization (1/rowsum) deferred to gemm_proj.
__global__ __launch_bounds__(512, 2) void attn_fused(
    const char* __restrict__ Qg, const char* __restrict__ Kg,
    const char* __restrict__ Vg,
    unsigned short* __restrict__ Ou, long long sOb,
    float* __restrict__ rsum, float scale2) {
    __shared__ __align__(16) char Ql[128 * 512];
    __shared__ __align__(16) char Kl[64 * 512];
    __shared__ __align__(16) char Vl[512 * 64];
    __shared__ __align__(16) char Pl[128 * 64];
    const int tid = threadIdx.x;
    const int wave = tid >> 6, lane = tid & 63;
    const int quad = lane >> 4, lc = lane & 15;
    // decode: xcd-major so each XCD owns one (bz, split) K/V half (L2 pinning)
    const int id = blockIdx.x;
    const int xcd = id & 7, qi = id >> 3;
    const int bz = xcd >> 1, split = xcd & 1;
    const int q0 = qi * 128;
    const int kvbase = split * 2048;
    const int NIT = 32;

    const char* Qb = Qg + ((size_t)bz * 4096 + q0) * 512;
    const char* Kb = Kg + ((size_t)bz * 4096 + kvbase) * 512;
    const char* Vb = Vg + (size_t)bz * 2097152 + kvbase;

    // S^T wave tiling: wave owns 16 q-cols (wq). O wave tiling: 2M x 4N over [128 q][512 d].
    const int wq = wave * 16;
    const int mO = (wave >> 2) * 64, nO = (wave & 3) * 128;

    // ---- staging (issue only; 16B/thread/call; LDS linear, source pre-swizzled) ----
    auto stageQ = [&]() {
#pragma unroll
        for (int c = 0; c < 8; ++c) {
            int f = c * 512 + tid;
            int r = f >> 5, g = f & 31;
            int gs = (g & 24) | ((g & 7) ^ (r & 7));
            __builtin_amdgcn_global_load_lds(
                (const __attribute__((address_space(1))) void*)(Qb + (size_t)r * 512 + gs * 16),
                (__attribute__((address_space(3))) void*)(Ql + (size_t)f * 16), 16, 0, 0);
        }
    };
    auto stageK = [&](int t) {
#pragma unroll
        for (int c = 0; c < 4; ++c) {
            int f = c * 512 + tid;
            int r = f >> 5, g = f & 31;
            int gs = (g & 24) | ((g & 7) ^ (r & 7));
            __builtin_amdgcn_global_load_lds(
                (const __attribute__((address_space(1))) void*)(Kb + (size_t)(t * 64 + r) * 512 + gs * 16),
                (__attribute__((address_space(3))) void*)(Kl + (size_t)f * 16), 16, 0, 0);
        }
    };
    auto stageV = [&](int t) {
#pragma unroll
        for (int c = 0; c < 4; ++c) {
            int f = c * 512 + tid;
            int r = f >> 2, g = f & 3;
            int gs = g ^ (r & 3);
            __builtin_amdgcn_global_load_lds(
                (const __attribute__((address_space(1))) void*)(Vb + (size_t)r * 4096 + t * 64 + gs * 16),
                (__attribute__((address_space(3))) void*)(Vl + (size_t)f * 16), 16, 0, 0);
        }
    };

    floatx4 acco[4][8];
#pragma unroll
    for (int i = 0; i < 4; ++i)
#pragma unroll
        for (int j = 0; j < 8; ++j) acco[i][j] = (floatx4){0.f, 0.f, 0.f, 0.f};
    float rs = 0.f;

    stageQ();
    stageK(0);
    stageV(0);
    syncfull();

    const int q = wq + lc;       // this lane's q-column in S^T
    const int q7 = q & 7;

    for (int t = 0; t < NIT; ++t) {
        // ---- phase A: S^T[kv=64][q=128] = K . Q^T over ch=512, then exp->P ----
        if (t > 0) stageV(t);  // Vl free since barrier-B(t-1); landed by end-of-A waitcnt
        i32x4 accs[4];
#pragma unroll
        for (int ki = 0; ki < 4; ++ki) accs[ki] = (i32x4){0, 0, 0, 0};
#pragma unroll
        for (int ks = 0; ks < 8; ++ks) {
            const int g = ks * 4 + quad;
            i32x4 bfrag = *(const i32x4*)&Ql[(size_t)q * 512 +
                                             (((g & 24) | ((g & 7) ^ q7)) << 4)];
#pragma unroll
            for (int ki = 0; ki < 4; ++ki) {
                const int ar = ki * 16 + lc;
                i32x4 afrag = *(const i32x4*)&Kl[(size_t)ar * 512 +
                                                 (((g & 24) | ((g & 7) ^ (ar & 7))) << 4)];
                accs[ki] = __builtin_amdgcn_mfma_i32_16x16x64_i8(afrag, bfrag, accs[ki], 0, 0, 0);
            }
        }
        float e[4][4];
#pragma unroll
        for (int ki = 0; ki < 4; ++ki)
#pragma unroll
            for (int r = 0; r < 4; ++r) {
                e[ki][r] = fminf(exp2f(fmaf((float)accs[ki][r], scale2, -2.0f)), 448.f);
                rs += e[ki][r];
            }
        // pack across ki => slots (quad*4+r)*4 + ki : matches v_f8's pack4 kv-permutation
#pragma unroll
        for (int r = 0; r < 4; ++r) {
            unsigned w = pack_fp8x4(e[0][r], e[1][r], e[2][r], e[3][r]);
            const int s4 = quad * 4 + r;
            const int byte = q * 64 + (((s4 >> 1) ^ q7) << 3) + ((s4 & 1) << 2);
            *(unsigned*)&Pl[byte] = w;
        }
        syncfull();  // P visible; V(t) landed; all waves done reading Kl(t)

        // ---- phase B: O += P . V^T over this kv-tile (2 k-steps of 32) ----
        if (t + 1 < NIT) stageK(t + 1);  // Kl free; landed by end-of-B waitcnt
#pragma unroll
        for (int ks2 = 0; ks2 < 2; ++ks2) {
            long pa[4], vf[8];
#pragma unroll
            for (int i = 0; i < 4; ++i) {
                const int row = mO + i * 16 + lc;
                pa[i] = *(const long*)&Pl[(size_t)row * 64 +
                                          (((ks2 * 4 + quad) ^ (row & 7)) << 3)];
            }
#pragma unroll
            for (int j = 0; j < 8; ++j) {
                const int row = nO + j * 16 + lc;
                const int g16 = ks2 * 2 + (quad >> 1);
                vf[j] = *(const long*)&Vl[(size_t)row * 64 +
                                          ((g16 ^ (row & 3)) << 4) + ((quad & 1) << 3)];
            }
#pragma unroll
            for (int i = 0; i < 4; ++i)
#pragma unroll
                for (int j = 0; j < 8; ++j)
                    acco[i][j] = __builtin_amdgcn_mfma_f32_16x16x32_fp8_fp8(pa[i], vf[j], acco[i][j], 0, 0, 0);
        }
        syncfull();  // K(t+1) landed; all waves done reading Vl(t), Pl(t)
    }

    // ---- epilogue: rowsum partial (this kv-half) + unnormalized O store (bf16, perm-d) ----
    rs += __shfl_xor(rs, 16);
    rs += __shfl_xor(rs, 32);
    if (quad == 0) rsum[((size_t)(split * 4 + bz)) * 4096 + q0 + q] = rs;

#pragma unroll
    for (int i = 0; i < 4; ++i) {
#pragma unroll
        for (int r = 0; r < 4; ++r) {
            const int m = q0 + mO + i * 16 + quad * 4 + r;
            unsigned short h[8];
#pragma unroll
            for (int j = 0; j < 8; ++j) h[j] = f2bs(acco[i][j][r]);
            unsigned short* base = Ou + (size_t)bz * sOb + (size_t)m * 1024 + split * 512 + nO;
            uint2 u0, u1;
            u0.x = (unsigned)h[0] | ((unsigned)h[1] << 16);
            u0.y = (unsigned)h[2] | ((unsigned)h[3] << 16);
            u1.x = (unsigned)h[4] | ((unsigned)h[5] << 16);
            u1.y = (unsigned)h[6] | ((unsigned)h[7] << 16);
            *(uint2*)(base + lc * 4) = u0;
            *(uint2*)(base + 64 + lc * 4) = u1;
        }
    }
}

// ---------------- NT GEMM, bf16, fp32-out epilogue (proj): y = A.B^T/rowsum[n] + bias[m] + resid ----------------
// K=1024: B = [O_un(split0); O_un(split1)] along k, A = wpb with k mod 512 (same weights both halves).
__global__ void gemm_proj(const unsigned short* __restrict__ A,
                          const unsigned short* __restrict__ B, long long sBb,
                          float* __restrict__ Cv, long long sCb,
                          const float* __restrict__ bias,
                          const float* __restrict__ resid, long long sRb,
                          const float* __restrict__ rsum,
                          int M, int N, int K) {
    __shared__ __align__(16) unsigned short lA[128 * 64];
    __shared__ __align__(16) unsigned short lB[128 * 64];
    const int tid = threadIdx.x;
    const int wave = tid >> 6, lane = tid & 63;
    const int m0 = blockIdx.y * 128, n0 = blockIdx.x * 128, bz = blockIdx.z;
    const unsigned short* Ab = A;
    const unsigned short* Bb = B + (size_t)bz * sBb;

    floatx4 acc[4][4];
#pragma unroll
    for (int i = 0; i < 4; i++)
#pragma unroll
        for (int j = 0; j < 4; j++) acc[i][j] = (floatx4){0.f, 0.f, 0.f, 0.f};

    const int wm = (wave >> 1) * 64, wn = (wave & 1) * 64;
    const int quad = lane >> 4;
    const int lc = lane & 15;
    const int lc7 = lc & 7;

    const int nk = K >> 6;
    for (int kt = 0; kt < nk; ++kt) {
        const int kbase = kt * 64;
#pragma unroll
        for (int c = 0; c < 4; ++c) {
            int d = c * 256 + tid;
            int r = d >> 3;
            int kc = (d & 7) ^ (r & 7);
            const unsigned short* ga = Ab + (size_t)(m0 + r) * 512 + ((kbase & 511) + kc * 8);
            const unsigned short* gb = Bb + (size_t)(n0 + r) * 1024 + kbase + kc * 8;
            __builtin_amdgcn_global_load_lds(
                (const __attribute__((address_space(1))) void*)ga,
                (__attribute__((address_space(3))) void*)&lA[(size_t)(c * 256 + wave * 64) * 8], 16, 0, 0);
            __builtin_amdgcn_global_load_lds(
                (const __attribute__((address_space(1))) void*)gb,
                (__attribute__((address_space(3))) void*)&lB[(size_t)(c * 256 + wave * 64) * 8], 16, 0, 0);
        }
        __syncthreads();
#pragma unroll
        for (int kk = 0; kk < 2; ++kk) {
            const int swz = ((kk * 4 + quad) ^ lc7) * 8;
            short8 af[4], bf[4];
#pragma unroll
            for (int i = 0; i < 4; i++)
                af[i] = *(const short8*)&lA[(size_t)(wm + i * 16 + lc) * 64 + swz];
#pragma unroll
            for (int j = 0; j < 4; j++)
                bf[j] = *(const short8*)&lB[(size_t)(wn + j * 16 + lc) * 64 + swz];
#pragma unroll
            for (int i = 0; i < 4; i++)
#pragma unroll
                for (int j = 0; j < 4; j++)
                    acc[i][j] = __builtin_amdgcn_mfma_f32_16x16x32_bf16(af[i], bf[j], acc[i][j], 0, 0, 0);
        }
        __syncthreads();
    }

    // per-n 1/rowsum (rowsum = split0 + split1 partials)
    float rsinv[4];
#pragma unroll
    for (int j = 0; j < 4; j++) {
        const int n = n0 + wn + j * 16 + lc;
        rsinv[j] = 1.f / (rsum[(size_t)bz * 4096 + n] + rsum[(size_t)(4 + bz) * 4096 + n]);
    }

    const int rowb = quad * 4;
#pragma unroll
    for (int i = 0; i < 4; i++) {
#pragma unroll
        for (int r = 0; r < 4; r++) {
            const int m = m0 + wm + i * 16 + rowb + r;
            const float bm = bias[m];
#pragma unroll
            for (int j = 0; j < 4; j++) {
                const int n = n0 + wn + j * 16 + lc;
                size_t idx = (size_t)bz * sCb + (size_t)m * N + n;
                Cv[idx] = acc[i][j][r] * rsinv[j] + bm + resid[(size_t)bz * sRb + (size_t)m * N + n];
            }
        }
    }
}

extern "C" void kernel_launch(void* const* d_in, const int* in_sizes, int n_in,
                              void* d_out, int out_size, void* d_ws, size_t ws_size,
                              hipStream_t stream) {
    (void)in_sizes; (void)n_in; (void)out_size; (void)ws_size;
    const float* x   = (const float*)d_in[0];
    const float* gnw = (const float*)d_in[1];
    const float* gnb = (const float*)d_in[2];
    const float* qw  = (const float*)d_in[3];
    const float* qb  = (const float*)d_in[4];
    const float* kw  = (const float*)d_in[5];
    const float* kb  = (const float*)d_in[6];
    const float* vw  = (const float*)d_in[7];
    const float* vb  = (const float*)d_in[8];
    const float* pw  = (const float*)d_in[9];
    const float* pb  = (const float*)d_in[10];
    float* out = (float*)d_out;

    char* ws = (char*)d_ws;
    unsigned short* h_t = (unsigned short*)(ws);
    char* q_i8 = (char*)(ws + (16ull << 20));
    char* k_i8 = (char*)(ws + (32ull << 20));
    char* v_f8 = (char*)(ws + (48ull << 20));
    unsigned short* wqkb = (unsigned short*)(ws + (64ull << 20));  // [qw;kw] 1024x512
    unsigned short* wvb = (unsigned short*)(ws + (65ull << 20));
    unsigned short* wpb = wvb + 262144;  // pack4-permuted k-cols
    float* stats  = (float*)(ws + (66ull << 20));
    float* biasqk = (float*)(ws + (66ull << 20) + 8192);
    float* rowsum = (float*)(ws + (66ull << 20) + 65536);          // [2 splits][4 bz][4096] f32
    unsigned short* o_un = (unsigned short*)(ws + (72ull << 20));  // [4 bz][4096 q][1024] bf16

    const long long sP  = 2097152;   // 4096*512 elements per batch
    const long long sOb = 4194304;   // 4096*1024 elements per batch (o_un)
    const float QS = 16.f;
    const float SC = 0.044194173824159216f / (QS * QS);
    const float LOG2E = 1.4426950408889634f;

    // setup + gn_stats merged
    pre_kernel<<<1153, 256, 0, stream>>>(x, qw, kw, vw, pw, qb, kb, wqkb, wvb, wpb,
                                         biasqk, stats);
    gn_apply_kernel<<<dim3(64, 8, 4), 256, 0, stream>>>(x, stats, gnw, gnb, h_t);
    // merged q|k (1024 blocks) + v (512 blocks)
    gemm_qkv<<<1536, 256, 0, stream>>>(h_t, sP, wqkb, wvb, q_i8, k_i8, v_f8, biasqk, vb, QS);
    // fused S^T->exp->P(LDS)->O_un, kv-split x2, rowsum partials
    attn_fused<<<dim3(256), 512, 0, stream>>>(q_i8, k_i8, v_f8, o_un, sOb, rowsum,
                                              SC * LOG2E);
    // y = x + wp~ . [O0;O1]^T / rowsum + pb: M=512(o), N=4096(p), K=1024
    gemm_proj<<<dim3(32, 4, 4), 256, 0, stream>>>(wpb, o_un, sOb, out, sP, pb, x, sP,
                                                  rowsum, 512, 4096, 1024);
}

// Round 3
// 291.347 us; speedup vs baseline: 1.0934x; 1.0763x over previous
//
#include <hip/hip_runtime.h>

#define DEV __device__ __forceinline__

typedef __attribute__((ext_vector_type(8))) short short8;
typedef __attribute__((ext_vector_type(4))) float floatx4;
typedef __attribute__((ext_vector_type(4))) int i32x4;
typedef __attribute__((ext_vector_type(2))) long longx2;

DEV unsigned short f2bs(float x) {
    unsigned u = __float_as_uint(x);
    unsigned r = (u + 0x7fffu + ((u >> 16) & 1u)) >> 16;
    return (unsigned short)r;
}

// f32 -> OCP e4m3fn. Caller pre-clamps to [-448, 448]. Fallback: branchless, FTZ below 2^-6.
DEV unsigned char f2fp8(float x) {
#if __has_builtin(__builtin_amdgcn_cvt_pk_fp8_f32)
    int pk = __builtin_amdgcn_cvt_pk_fp8_f32(x, 0.f, 0, false);
    return (unsigned char)(pk & 0xff);
#else
    unsigned u = __float_as_uint(x);
    unsigned s = (u >> 24) & 0x80;
    unsigned a = u & 0x7fffffff;
    unsigned um = a + 0x7ffffu + ((a >> 20) & 1u);
    unsigned r = (a >= 0x3c800000u) ? ((um >> 20) - 0x3C0u) : 0u;
    return (unsigned char)(r | s);
#endif
}

DEV unsigned pack_fp8x4(float v0, float v1, float v2, float v3) {
#if __has_builtin(__builtin_amdgcn_cvt_pk_fp8_f32)
    unsigned pk = (unsigned)__builtin_amdgcn_cvt_pk_fp8_f32(v0, v1, 0, false);
    pk = (unsigned)__builtin_amdgcn_cvt_pk_fp8_f32(v2, v3, (int)pk, true);
    return pk;
#else
    return (unsigned)f2fp8(v0) | ((unsigned)f2fp8(v1) << 8) |
           ((unsigned)f2fp8(v2) << 16) | ((unsigned)f2fp8(v3) << 24);
#endif
}

DEV unsigned pack_i8x4(float v0, float v1, float v2, float v3) {
    unsigned b0 = (unsigned)((int)rintf(v0)) & 255u;
    unsigned b1 = (unsigned)((int)rintf(v1)) & 255u;
    unsigned b2 = (unsigned)((int)rintf(v2)) & 255u;
    unsigned b3 = (unsigned)((int)rintf(v3)) & 255u;
    return b0 | (b1 << 8) | (b2 << 16) | (b3 << 24);
}

DEV void syncfull() {
    asm volatile("s_waitcnt vmcnt(0) lgkmcnt(0)" ::: "memory");
    __builtin_amdgcn_sched_barrier(0);
    __builtin_amdgcn_s_barrier();
    __builtin_amdgcn_sched_barrier(0);
}

// ---------------- merged pre-pass: setup (blocks 0..1024) + gn_stats (1025..1152) ----------------
__global__ void pre_kernel(const float* __restrict__ x,
                           const float* __restrict__ qw, const float* __restrict__ kw,
                           const float* __restrict__ vw, const float* __restrict__ pw,
                           const float* __restrict__ qb, const float* __restrict__ kb,
                           unsigned short* __restrict__ wqkb, unsigned short* __restrict__ wvb,
                           unsigned short* __restrict__ wpb,
                           float* __restrict__ biasqk,
                           float* __restrict__ stats) {
    int b = blockIdx.x, tid = threadIdx.x;
    if (b < 768) {
        const float* src = (b < 256) ? qw : (b < 512) ? kw : vw;
        unsigned short* dst = (b < 256) ? wqkb : (b < 512) ? (wqkb + 262144) : wvb;
        int off = (b & 255) * 256 + tid;
        float4 v = ((const float4*)src)[off];
        ushort4 o;
        o.x = f2bs(v.x); o.y = f2bs(v.y); o.z = f2bs(v.z); o.w = f2bs(v.w);
        ((ushort4*)dst)[off] = o;
    } else if (b < 1024) {
        int off = (b - 768) * 256 + tid;
        int row = off >> 7, c4 = (off & 127) * 4;
        float4 v = ((const float4*)pw)[off];
        float vv[4] = {v.x, v.y, v.z, v.w};
#pragma unroll
        for (int e = 0; e < 4; ++e) {
            int c = c4 + e;
            int j = (c >> 4) & 3, lc = c & 15;
            int cp = (c & ~63) | (lc * 4 + j);
            wpb[row * 512 + cp] = f2bs(vv[e]);
        }
    } else if (b == 1024) {
        biasqk[tid]       = qb[tid];
        biasqk[256 + tid] = qb[256 + tid];
        biasqk[512 + tid] = kb[tid];
        biasqk[768 + tid] = kb[256 + tid];
    } else {
        int bg = b - 1025;  // 0..127
        const float4* p = (const float4*)(x + (size_t)bg * 65536);
        float s = 0.f, ss = 0.f;
        for (int i = tid; i < 16384; i += 256) {
            float4 v = p[i];
            s += v.x + v.y + v.z + v.w;
            ss += v.x * v.x + v.y * v.y + v.z * v.z + v.w * v.w;
        }
        for (int off = 32; off; off >>= 1) { s += __shfl_down(s, off); ss += __shfl_down(ss, off); }
        __shared__ float rs[4], rss[4];
        int wave = tid >> 6, lane = tid & 63;
        if (lane == 0) { rs[wave] = s; rss[wave] = ss; }
        __syncthreads();
        if (tid == 0) {
            float S = rs[0] + rs[1] + rs[2] + rs[3];
            float SS = rss[0] + rss[1] + rss[2] + rss[3];
            float mean = S * (1.f / 65536.f);
            float var = SS * (1.f / 65536.f) - mean * mean;
            stats[bg * 2] = mean;
            stats[bg * 2 + 1] = rsqrtf(var + 1e-5f);
        }
    }
}

// ------------- GN apply + transpose: x[b][c][p] fp32 -> h_t[b][p][c] bf16 -------------
__global__ void gn_apply_kernel(const float* __restrict__ x, const float* __restrict__ stats,
                                const float* __restrict__ gw, const float* __restrict__ gb,
                                unsigned short* __restrict__ ht) {
    __shared__ __align__(16) unsigned short t[64][72];
    int b = blockIdx.z, c0 = blockIdx.y * 64, p0 = blockIdx.x * 64;
    int tid = threadIdx.x;
    const float* xb = x + ((size_t)b * 512 + c0) * 4096 + p0;
#pragma unroll
    for (int pass = 0; pass < 4; ++pass) {
        int cl = pass * 16 + (tid >> 4);
        int pq = (tid & 15) * 4;
        float4 v = *(const float4*)(xb + (size_t)cl * 4096 + pq);
        int c = c0 + cl, g = c >> 4;
        float mean = stats[(b * 32 + g) * 2], rstd = stats[(b * 32 + g) * 2 + 1];
        float sw = gw[c] * rstd;
        float sb = gb[c] - mean * sw;
        t[pq + 0][cl] = f2bs(v.x * sw + sb);
        t[pq + 1][cl] = f2bs(v.y * sw + sb);
        t[pq + 2][cl] = f2bs(v.z * sw + sb);
        t[pq + 3][cl] = f2bs(v.w * sw + sb);
    }
    __syncthreads();
    unsigned short* hb = ht + ((size_t)b * 4096 + p0) * 512 + c0;
#pragma unroll
    for (int pass = 0; pass < 2; ++pass) {
        int pl = pass * 32 + (tid >> 3);
        int c8 = (tid & 7) * 8;
        *(uint4*)(hb + (size_t)pl * 512 + c8) = *(const uint4*)&t[pl][c8];
    }
}

// ---------------- merged qkv NT GEMM (K=512, bf16): blocks 0..1023 = q|k, 1024..1535 = v ----------------
__global__ void gemm_qkv(const unsigned short* __restrict__ h_t, long long sP,
                         const unsigned short* __restrict__ wqkb,
                         const unsigned short* __restrict__ wvb,
                         char* __restrict__ q_i8, char* __restrict__ k_i8,
                         char* __restrict__ v_f8,
                         const float* __restrict__ biasqk, const float* __restrict__ vb,
                         float qs) {
    __shared__ __align__(16) unsigned short lA[128 * 64];
    __shared__ __align__(16) unsigned short lB[128 * 64];
    const int tid = threadIdx.x;
    const int wave = tid >> 6, lane = tid & 63;
    const int flat = blockIdx.x;
    const bool isqk = flat < 1024;
    int m0, n0, bz;
    const unsigned short *Ab, *Bb;
    if (isqk) {
        m0 = ((flat >> 3) & 31) * 128;
        n0 = (flat & 7) * 128;
        bz = flat >> 8;
        Ab = h_t + (size_t)bz * sP;
        Bb = wqkb;
    } else {
        const int g = flat - 1024;
        m0 = ((g >> 5) & 3) * 128;
        n0 = (g & 31) * 128;
        bz = g >> 7;
        Ab = wvb;
        Bb = h_t + (size_t)bz * sP;
    }

    floatx4 acc[4][4];
#pragma unroll
    for (int i = 0; i < 4; i++)
#pragma unroll
        for (int j = 0; j < 4; j++) acc[i][j] = (floatx4){0.f, 0.f, 0.f, 0.f};

    const int wm = (wave >> 1) * 64, wn = (wave & 1) * 64;
    const int quad = lane >> 4;
    const int lc = lane & 15;
    const int lc7 = lc & 7;

    for (int kt = 0; kt < 8; ++kt) {
        const int kbase = kt * 64;
#pragma unroll
        for (int c = 0; c < 4; ++c) {
            int d = c * 256 + tid;
            int r = d >> 3;
            int kc = (d & 7) ^ (r & 7);
            const unsigned short* ga = Ab + (size_t)(m0 + r) * 512 + kbase + kc * 8;
            const unsigned short* gb = Bb + (size_t)(n0 + r) * 512 + kbase + kc * 8;
            __builtin_amdgcn_global_load_lds(
                (const __attribute__((address_space(1))) void*)ga,
                (__attribute__((address_space(3))) void*)&lA[(size_t)(c * 256 + wave * 64) * 8], 16, 0, 0);
            __builtin_amdgcn_global_load_lds(
                (const __attribute__((address_space(1))) void*)gb,
                (__attribute__((address_space(3))) void*)&lB[(size_t)(c * 256 + wave * 64) * 8], 16, 0, 0);
        }
        __syncthreads();
#pragma unroll
        for (int kk = 0; kk < 2; ++kk) {
            const int swz = ((kk * 4 + quad) ^ lc7) * 8;
            short8 af[4], bf[4];
#pragma unroll
            for (int i = 0; i < 4; i++)
                af[i] = *(const short8*)&lA[(size_t)(wm + i * 16 + lc) * 64 + swz];
#pragma unroll
            for (int j = 0; j < 4; j++)
                bf[j] = *(const short8*)&lB[(size_t)(wn + j * 16 + lc) * 64 + swz];
#pragma unroll
            for (int i = 0; i < 4; i++)
#pragma unroll
                for (int j = 0; j < 4; j++)
                    acc[i][j] = __builtin_amdgcn_mfma_f32_16x16x32_bf16(af[i], bf[j], acc[i][j], 0, 0, 0);
        }
        __syncthreads();
    }

    const int rowb = quad * 4;
    if (isqk) {
#pragma unroll
        for (int i = 0; i < 4; i++) {
#pragma unroll
            for (int r = 0; r < 4; r++) {
                const int m = m0 + wm + i * 16 + rowb + r;
                float q[4];
#pragma unroll
                for (int j = 0; j < 4; j++) {
                    const int n = n0 + wn + j * 16 + lc;
                    q[j] = fminf(fmaxf((acc[i][j][r] + biasqk[n]) * qs, -127.f), 127.f);
                }
                const int col64 = n0 + wn;
                char* outp = (col64 < 512) ? q_i8 : k_i8;
                size_t idx = (size_t)bz * sP + (size_t)m * 512 +
                             (col64 - ((col64 < 512) ? 0 : 512)) + lc * 4;
                *(unsigned*)(outp + idx) = pack_i8x4(q[0], q[1], q[2], q[3]);
            }
        }
    } else {
#pragma unroll
        for (int i = 0; i < 4; i++) {
#pragma unroll
            for (int r = 0; r < 4; r++) {
                const int m = m0 + wm + i * 16 + rowb + r;
                const float bm = vb[m];
                float q[4];
#pragma unroll
                for (int j = 0; j < 4; j++)
                    q[j] = fminf(fmaxf(acc[i][j][r] + bm, -448.f), 448.f);
                size_t idx = (size_t)bz * sP + (size_t)m * 4096 + n0 + wn + lc * 4;
                *(unsigned*)(v_f8 + idx) = pack_fp8x4(q[0], q[1], q[2], q[3]);
            }
        }
    }
}

// ---------------- NT GEMM, bf16, fp32-out epilogue (proj): y = A.B^T/rowsum[n] + bias[m] + resid ----------------
__global__ void gemm_proj(const unsigned short* __restrict__ A,
                          const unsigned short* __restrict__ B, long long sBb,
                          float* __restrict__ Cv, long long sCb,
                          const float* __restrict__ bias,
                          const float* __restrict__ resid, long long sRb,
                          const float* __restrict__ rsum,
                          int M, int N, int K) {
    __shared__ __align__(16) unsigned short lA[128 * 64];
    __shared__ __align__(16) unsigned short lB[128 * 64];
    const int tid = threadIdx.x;
    const int wave = tid >> 6, lane = tid & 63;
    const int m0 = blockIdx.y * 128, n0 = blockIdx.x * 128, bz = blockIdx.z;
    const unsigned short* Ab = A;
    const unsigned short* Bb = B + (size_t)bz * sBb;

    floatx4 acc[4][4];
#pragma unroll
    for (int i = 0; i < 4; i++)
#pragma unroll
        for (int j = 0; j < 4; j++) acc[i][j] = (floatx4){0.f, 0.f, 0.f, 0.f};

    const int wm = (wave >> 1) * 64, wn = (wave & 1) * 64;
    const int quad = lane >> 4;
    const int lc = lane & 15;
    const int lc7 = lc & 7;

    const int nk = K >> 6;
    for (int kt = 0; kt < nk; ++kt) {
        const int kbase = kt * 64;
#pragma unroll
        for (int c = 0; c < 4; ++c) {
            int d = c * 256 + tid;
            int r = d >> 3;
            int kc = (d & 7) ^ (r & 7);
            const unsigned short* ga = Ab + (size_t)(m0 + r) * 512 + ((kbase & 511) + kc * 8);
            const unsigned short* gb = Bb + (size_t)(n0 + r) * 1024 + kbase + kc * 8;
            __builtin_amdgcn_global_load_lds(
                (const __attribute__((address_space(1))) void*)ga,
                (__attribute__((address_space(3))) void*)&lA[(size_t)(c * 256 + wave * 64) * 8], 16, 0, 0);
            __builtin_amdgcn_global_load_lds(
                (const __attribute__((address_space(1))) void*)gb,
                (__attribute__((address_space(3))) void*)&lB[(size_t)(c * 256 + wave * 64) * 8], 16, 0, 0);
        }
        __syncthreads();
#pragma unroll
        for (int kk = 0; kk < 2; ++kk) {
            const int swz = ((kk * 4 + quad) ^ lc7) * 8;
            short8 af[4], bf[4];
#pragma unroll
            for (int i = 0; i < 4; i++)
                af[i] = *(const short8*)&lA[(size_t)(wm + i * 16 + lc) * 64 + swz];
#pragma unroll
            for (int j = 0; j < 4; j++)
                bf[j] = *(const short8*)&lB[(size_t)(wn + j * 16 + lc) * 64 + swz];
#pragma unroll
            for (int i = 0; i < 4; i++)
#pragma unroll
                for (int j = 0; j < 4; j++)
                    acc[i][j] = __builtin_amdgcn_mfma_f32_16x16x32_bf16(af[i], bf[j], acc[i][j], 0, 0, 0);
        }
        __syncthreads();
    }

    float rsinv[4];
#pragma unroll
    for (int j = 0; j < 4; j++) {
        const int n = n0 + wn + j * 16 + lc;
        rsinv[j] = 1.f / (rsum[(size_t)bz * 4096 + n] + rsum[(size_t)(4 + bz) * 4096 + n]);
    }

    const int rowb = quad * 4;
#pragma unroll
    for (int i = 0; i < 4; i++) {
#pragma unroll
        for (int r = 0; r < 4; r++) {
            const int m = m0 + wm + i * 16 + rowb + r;
            const float bm = bias[m];
#pragma unroll
            for (int j = 0; j < 4; j++) {
                const int n = n0 + wn + j * 16 + lc;
                size_t idx = (size_t)bz * sCb + (size_t)m * N + n;
                Cv[idx] = acc[i][j][r] * rsinv[j] + bm + resid[(size_t)bz * sRb + (size_t)m * N + n];
            }
        }
    }
}

// ---------------- fused attention: S^T = K.Q^T (i8) -> exp -> P (LDS, fp8) -> O_un += P.V^T (fp8) ----------------
// Grid: 256 blocks = 8 xcd-groups (bz*2+split) x 32 q-tiles. 512 thr (8 waves). 1 block/CU.
// All LDS tiles use the proven 128B-row-pitch geometry (8 x 16B slots, XOR row&7) to kill bank conflicts:
//   Ql[512][128]: row = chq*128+q,  slot = ((ch>>4)&7) ^ (q&7)
//   Kl[256][128]: row = chq*64+kv,  slot = ((ch>>4)&7) ^ (kv&7)
//   Vl[256][128]: row = d&255, slot = ((d>>8)*4 + gq) ^ (d&7); 16B slot = global group gq (chunk-paired)
//   Pl[128][80]:  padded pitch 80 (16B-aligned, 20q mod 32 spreads banks); slot quad = chunk pair (r01|r23)
// Phase B: one b128 per fragment yields both k-steps (lo=ks2:0, hi=ks2:1).
__global__ __launch_bounds__(512, 2) void attn_fused(
    const char* __restrict__ Qg, const char* __restrict__ Kg,
    const char* __restrict__ Vg,
    unsigned short* __restrict__ Ou, long long sOb,
    float* __restrict__ rsum, float scale2) {
    __shared__ __align__(16) char Ql[512 * 128];
    __shared__ __align__(16) char Kl[256 * 128];
    __shared__ __align__(16) char Vl[256 * 128];
    __shared__ __align__(16) char Pl[128 * 80];
    const int tid = threadIdx.x;
    const int wave = tid >> 6, lane = tid & 63;
    const int quad = lane >> 4, lc = lane & 15;
    const int lc7 = lc & 7;
    const int id = blockIdx.x;
    const int xcd = id & 7, qi = id >> 3;
    const int bz = xcd >> 1, split = xcd & 1;
    const int q0 = qi * 128;
    const int kvbase = split * 2048;
    const int NIT = 32;

    const char* Qb = Qg + ((size_t)bz * 4096 + q0) * 512;
    const char* Kb = Kg + ((size_t)bz * 4096 + kvbase) * 512;
    const char* Vb = Vg + (size_t)bz * 2097152 + kvbase;

    const int wq = wave * 16;
    const int mO = (wave >> 2) * 64, nO = (wave & 3) * 128;

    // ---- staging (issue only; 16B/thread/call; LDS linear in thread order) ----
    auto stageQ = [&]() {
#pragma unroll
        for (int c = 0; c < 8; ++c) {
            int f = c * 512 + tid;
            int rr = f >> 3, cs = f & 7;
            int qq = rr & 127, chq = rr >> 7;
            int s = cs ^ (qq & 7);
            __builtin_amdgcn_global_load_lds(
                (const __attribute__((address_space(1))) void*)(Qb + (size_t)qq * 512 + chq * 128 + s * 16),
                (__attribute__((address_space(3))) void*)(Ql + (size_t)f * 16), 16, 0, 0);
        }
    };
    auto stageK = [&](int t) {
#pragma unroll
        for (int c = 0; c < 4; ++c) {
            int f = c * 512 + tid;
            int rr = f >> 3, cs = f & 7;
            int kv = rr & 63, chq = rr >> 6;
            int s = cs ^ (kv & 7);
            __builtin_amdgcn_global_load_lds(
                (const __attribute__((address_space(1))) void*)(Kb + (size_t)(t * 64 + kv) * 512 + chq * 128 + s * 16),
                (__attribute__((address_space(3))) void*)(Kl + (size_t)f * 16), 16, 0, 0);
        }
    };
    auto stageV = [&](int t) {
#pragma unroll
        for (int c = 0; c < 4; ++c) {
            int f = c * 512 + tid;
            int rr = f >> 3, cs = f & 7;
            int cp = cs ^ (rr & 7);
            int d = rr + ((cp >> 2) << 8);
            int gq = cp & 3;
            __builtin_amdgcn_global_load_lds(
                (const __attribute__((address_space(1))) void*)(Vb + (size_t)d * 4096 + t * 64 + gq * 16),
                (__attribute__((address_space(3))) void*)(Vl + (size_t)f * 16), 16, 0, 0);
        }
    };

    floatx4 acco[4][8];
#pragma unroll
    for (int i = 0; i < 4; ++i)
#pragma unroll
        for (int j = 0; j < 8; ++j) acco[i][j] = (floatx4){0.f, 0.f, 0.f, 0.f};
    float rs = 0.f;

    stageQ();
    stageK(0);
    stageV(0);
    syncfull();

    const int q = wq + lc;       // this lane's q-column in S^T
    const int q7 = q & 7;

    for (int t = 0; t < NIT; ++t) {
        // ---- phase A: S^T[kv=64][q=128] = K . Q^T over ch=512, then exp->P ----
        if (t > 0) stageV(t);  // Vl free since barrier-B(t-1); landed by end-of-A waitcnt
        i32x4 accs[4];
#pragma unroll
        for (int ki = 0; ki < 4; ++ki) accs[ki] = (i32x4){0, 0, 0, 0};
#pragma unroll
        for (int ks = 0; ks < 8; ++ks) {
            const int g = ks * 4 + quad;
            const int gh = g >> 3, gl = g & 7;
            i32x4 bfrag = *(const i32x4*)&Ql[(size_t)(gh * 128 + q) * 128 + ((gl ^ q7) << 4)];
#pragma unroll
            for (int ki = 0; ki < 4; ++ki) {
                const int ar = ki * 16 + lc;
                i32x4 afrag = *(const i32x4*)&Kl[(size_t)(gh * 64 + ar) * 128 + ((gl ^ lc7) << 4)];
                accs[ki] = __builtin_amdgcn_mfma_i32_16x16x64_i8(afrag, bfrag, accs[ki], 0, 0, 0);
            }
        }
        float e[4][4];
#pragma unroll
        for (int ki = 0; ki < 4; ++ki)
#pragma unroll
            for (int r = 0; r < 4; ++r) {
                e[ki][r] = fminf(exp2f(fmaf((float)accs[ki][r], scale2, -2.0f)), 448.f);
                rs += e[ki][r];
            }
        // chunk (quad, r2) at slot quad, half r2: bytes y: kv = (y&3)*16 + quad*4 + 2*r2 + (y>>2)
        {
            unsigned w0 = pack_fp8x4(e[0][0], e[1][0], e[2][0], e[3][0]);
            unsigned w1 = pack_fp8x4(e[0][1], e[1][1], e[2][1], e[3][1]);
            unsigned w2 = pack_fp8x4(e[0][2], e[1][2], e[2][2], e[3][2]);
            unsigned w3 = pack_fp8x4(e[0][3], e[1][3], e[2][3], e[3][3]);
            uint2 s0; s0.x = w0; s0.y = w1;
            uint2 s1; s1.x = w2; s1.y = w3;
            *(uint2*)&Pl[(size_t)q * 80 + quad * 16 + 0] = s0;
            *(uint2*)&Pl[(size_t)q * 80 + quad * 16 + 8] = s1;
        }
        syncfull();  // P visible; V(t) landed; all waves done reading Kl(t)

        // ---- phase B: O += P . V^T over this kv-tile; b128 per fragment = both k-steps ----
        if (t + 1 < NIT) stageK(t + 1);  // Kl free; landed by end-of-B waitcnt
        {
            longx2 pv[4], vv[8];
#pragma unroll
            for (int i = 0; i < 4; ++i) {
                const int row = mO + i * 16 + lc;
                pv[i] = *(const longx2*)&Pl[(size_t)row * 80 + quad * 16];
            }
#pragma unroll
            for (int j = 0; j < 8; ++j) {
                const int row = nO + j * 16 + lc;
                const int r8 = row & 255, hi = row >> 8;
                vv[j] = *(const longx2*)&Vl[(size_t)r8 * 128 + (((hi << 2) + quad) ^ lc7) * 16];
            }
#pragma unroll
            for (int i = 0; i < 4; ++i)
#pragma unroll
                for (int j = 0; j < 8; ++j)
                    acco[i][j] = __builtin_amdgcn_mfma_f32_16x16x32_fp8_fp8(pv[i][0], vv[j][0], acco[i][j], 0, 0, 0);
#pragma unroll
            for (int i = 0; i < 4; ++i)
#pragma unroll
                for (int j = 0; j < 8; ++j)
                    acco[i][j] = __builtin_amdgcn_mfma_f32_16x16x32_fp8_fp8(pv[i][1], vv[j][1], acco[i][j], 0, 0, 0);
        }
        syncfull();  // K(t+1) landed; all waves done reading Vl(t), Pl(t)
    }

    // ---- epilogue: rowsum partial (this kv-half) + unnormalized O store (bf16, perm-d) ----
    rs += __shfl_xor(rs, 16);
    rs += __shfl_xor(rs, 32);
    if (quad == 0) rsum[((size_t)(split * 4 + bz)) * 4096 + q0 + q] = rs;

#pragma unroll
    for (int i = 0; i < 4; ++i) {
#pragma unroll
        for (int r = 0; r < 4; ++r) {
            const int m = q0 + mO + i * 16 + quad * 4 + r;
            unsigned short h[8];
#pragma unroll
            for (int j = 0; j < 8; ++j) h[j] = f2bs(acco[i][j][r]);
            unsigned short* base = Ou + (size_t)bz * sOb + (size_t)m * 1024 + split * 512 + nO;
            uint2 u0, u1;
            u0.x = (unsigned)h[0] | ((unsigned)h[1] << 16);
            u0.y = (unsigned)h[2] | ((unsigned)h[3] << 16);
            u1.x = (unsigned)h[4] | ((unsigned)h[5] << 16);
            u1.y = (unsigned)h[6] | ((unsigned)h[7] << 16);
            *(uint2*)(base + lc * 4) = u0;
            *(uint2*)(base + 64 + lc * 4) = u1;
        }
    }
}

extern "C" void kernel_launch(void* const* d_in, const int* in_sizes, int n_in,
                              void* d_out, int out_size, void* d_ws, size_t ws_size,
                              hipStream_t stream) {
    (void)in_sizes; (void)n_in; (void)out_size; (void)ws_size;
    const float* x   = (const float*)d_in[0];
    const float* gnw = (const float*)d_in[1];
    const float* gnb = (const float*)d_in[2];
    const float* qw  = (const float*)d_in[3];
    const float* qb  = (const float*)d_in[4];
    const float* kw  = (const float*)d_in[5];
    const float* kb  = (const float*)d_in[6];
    const float* vw  = (const float*)d_in[7];
    const float* vb  = (const float*)d_in[8];
    const float* pw  = (const float*)d_in[9];
    const float* pb  = (const float*)d_in[10];
    float* out = (float*)d_out;

    char* ws = (char*)d_ws;
    unsigned short* h_t = (unsigned short*)(ws);
    char* q_i8 = (char*)(ws + (16ull << 20));
    char* k_i8 = (char*)(ws + (32ull << 20));
    char* v_f8 = (char*)(ws + (48ull << 20));
    unsigned short* wqkb = (unsigned short*)(ws + (64ull << 20));  // [qw;kw] 1024x512
    unsigned short* wvb = (unsigned short*)(ws + (65ull << 20));
    unsigned short* wpb = wvb + 262144;  // pack4-permuted k-cols
    float* stats  = (float*)(ws + (66ull << 20));
    float* biasqk = (float*)(ws + (66ull << 20) + 8192);
    float* rowsum = (float*)(ws + (66ull << 20) + 65536);          // [2 splits][4 bz][4096] f32
    unsigned short* o_un = (unsigned short*)(ws + (72ull << 20));  // [4 bz][4096 q][1024] bf16

    const long long sP  = 2097152;   // 4096*512 elements per batch
    const long long sOb = 4194304;   // 4096*1024 elements per batch (o_un)
    const float QS = 16.f;
    const float SC = 0.044194173824159216f / (QS * QS);
    const float LOG2E = 1.4426950408889634f;

    // setup + gn_stats merged
    pre_kernel<<<1153, 256, 0, stream>>>(x, qw, kw, vw, pw, qb, kb, wqkb, wvb, wpb,
                                         biasqk, stats);
    gn_apply_kernel<<<dim3(64, 8, 4), 256, 0, stream>>>(x, stats, gnw, gnb, h_t);
    // merged q|k (1024 blocks) + v (512 blocks)
    gemm_qkv<<<1536, 256, 0, stream>>>(h_t, sP, wqkb, wvb, q_i8, k_i8, v_f8, biasqk, vb, QS);
    // fused S^T->exp->P(LDS)->O_un, kv-split x2, rowsum partials
    attn_fused<<<dim3(256), 512, 0, stream>>>(q_i8, k_i8, v_f8, o_un, sOb, rowsum,
                                              SC * LOG2E);
    // y = x + wp~ . [O0;O1]^T / rowsum + pb: M=512(o), N=4096(p), K=1024
    gemm_proj<<<dim3(32, 4, 4), 256, 0, stream>>>(wpb, o_un, sOb, out, sP, pb, x, sP,
                                                  rowsum, 512, 4096, 1024);
}

// Round 4
// 278.774 us; speedup vs baseline: 1.1428x; 1.0451x over previous
//
#include <hip/hip_runtime.h>

#define DEV __device__ __forceinline__

typedef __attribute__((ext_vector_type(8))) short short8;
typedef __attribute__((ext_vector_type(4))) float floatx4;
typedef __attribute__((ext_vector_type(16))) float floatx16;
typedef __attribute__((ext_vector_type(4))) int i32x4;
typedef __attribute__((ext_vector_type(8))) int i32x8;
typedef __attribute__((ext_vector_type(2))) long longx2;

DEV unsigned short f2bs(float x) {
    unsigned u = __float_as_uint(x);
    unsigned r = (u + 0x7fffu + ((u >> 16) & 1u)) >> 16;
    return (unsigned short)r;
}

// f32 -> OCP e4m3fn. Caller pre-clamps to [-448, 448]. Fallback: branchless, FTZ below 2^-6.
DEV unsigned char f2fp8(float x) {
#if __has_builtin(__builtin_amdgcn_cvt_pk_fp8_f32)
    int pk = __builtin_amdgcn_cvt_pk_fp8_f32(x, 0.f, 0, false);
    return (unsigned char)(pk & 0xff);
#else
    unsigned u = __float_as_uint(x);
    unsigned s = (u >> 24) & 0x80;
    unsigned a = u & 0x7fffffff;
    unsigned um = a + 0x7ffffu + ((a >> 20) & 1u);
    unsigned r = (a >= 0x3c800000u) ? ((um >> 20) - 0x3C0u) : 0u;
    return (unsigned char)(r | s);
#endif
}

DEV unsigned pack_fp8x4(float v0, float v1, float v2, float v3) {
#if __has_builtin(__builtin_amdgcn_cvt_pk_fp8_f32)
    unsigned pk = (unsigned)__builtin_amdgcn_cvt_pk_fp8_f32(v0, v1, 0, false);
    pk = (unsigned)__builtin_amdgcn_cvt_pk_fp8_f32(v2, v3, (int)pk, true);
    return pk;
#else
    return (unsigned)f2fp8(v0) | ((unsigned)f2fp8(v1) << 8) |
           ((unsigned)f2fp8(v2) << 16) | ((unsigned)f2fp8(v3) << 24);
#endif
}

DEV unsigned pack_i8x4(float v0, float v1, float v2, float v3) {
    unsigned b0 = (unsigned)((int)rintf(v0)) & 255u;
    unsigned b1 = (unsigned)((int)rintf(v1)) & 255u;
    unsigned b2 = (unsigned)((int)rintf(v2)) & 255u;
    unsigned b3 = (unsigned)((int)rintf(v3)) & 255u;
    return b0 | (b1 << 8) | (b2 << 16) | (b3 << 24);
}

DEV void syncfull() {
    asm volatile("s_waitcnt vmcnt(0) lgkmcnt(0)" ::: "memory");
    __builtin_amdgcn_sched_barrier(0);
    __builtin_amdgcn_s_barrier();
    __builtin_amdgcn_sched_barrier(0);
}

// ---------------- merged pre-pass: setup (blocks 0..1024) + gn_stats (1025..1152) ----------------
// wp's k-columns get the O-store permutation (within each 64-block: d -> (d&31)*2 + (d>>5))
// to match o_un's store layout in attn_fused's 32x32 epilogue.
__global__ void pre_kernel(const float* __restrict__ x,
                           const float* __restrict__ qw, const float* __restrict__ kw,
                           const float* __restrict__ vw, const float* __restrict__ pw,
                           const float* __restrict__ qb, const float* __restrict__ kb,
                           unsigned short* __restrict__ wqkb, unsigned short* __restrict__ wvb,
                           unsigned short* __restrict__ wpb,
                           float* __restrict__ biasqk,
                           float* __restrict__ stats) {
    int b = blockIdx.x, tid = threadIdx.x;
    if (b < 768) {
        const float* src = (b < 256) ? qw : (b < 512) ? kw : vw;
        unsigned short* dst = (b < 256) ? wqkb : (b < 512) ? (wqkb + 262144) : wvb;
        int off = (b & 255) * 256 + tid;
        float4 v = ((const float4*)src)[off];
        ushort4 o;
        o.x = f2bs(v.x); o.y = f2bs(v.y); o.z = f2bs(v.z); o.w = f2bs(v.w);
        ((ushort4*)dst)[off] = o;
    } else if (b < 1024) {
        int off = (b - 768) * 256 + tid;
        int row = off >> 7, c4 = (off & 127) * 4;
        float4 v = ((const float4*)pw)[off];
        float vv[4] = {v.x, v.y, v.z, v.w};
#pragma unroll
        for (int e = 0; e < 4; ++e) {
            int c = c4 + e;
            int cp = (c & ~63) | (((c & 31) << 1) | ((c >> 5) & 1));
            wpb[row * 512 + cp] = f2bs(vv[e]);
        }
    } else if (b == 1024) {
        biasqk[tid]       = qb[tid];
        biasqk[256 + tid] = qb[256 + tid];
        biasqk[512 + tid] = kb[tid];
        biasqk[768 + tid] = kb[256 + tid];
    } else {
        int bg = b - 1025;  // 0..127
        const float4* p = (const float4*)(x + (size_t)bg * 65536);
        float s = 0.f, ss = 0.f;
        for (int i = tid; i < 16384; i += 256) {
            float4 v = p[i];
            s += v.x + v.y + v.z + v.w;
            ss += v.x * v.x + v.y * v.y + v.z * v.z + v.w * v.w;
        }
        for (int off = 32; off; off >>= 1) { s += __shfl_down(s, off); ss += __shfl_down(ss, off); }
        __shared__ float rs[4], rss[4];
        int wave = tid >> 6, lane = tid & 63;
        if (lane == 0) { rs[wave] = s; rss[wave] = ss; }
        __syncthreads();
        if (tid == 0) {
            float S = rs[0] + rs[1] + rs[2] + rs[3];
            float SS = rss[0] + rss[1] + rss[2] + rss[3];
            float mean = S * (1.f / 65536.f);
            float var = SS * (1.f / 65536.f) - mean * mean;
            stats[bg * 2] = mean;
            stats[bg * 2 + 1] = rsqrtf(var + 1e-5f);
        }
    }
}

// ------------- GN apply + transpose: x[b][c][p] fp32 -> h_t[b][p][c] bf16 -------------
__global__ void gn_apply_kernel(const float* __restrict__ x, const float* __restrict__ stats,
                                const float* __restrict__ gw, const float* __restrict__ gb,
                                unsigned short* __restrict__ ht) {
    __shared__ __align__(16) unsigned short t[64][72];
    int b = blockIdx.z, c0 = blockIdx.y * 64, p0 = blockIdx.x * 64;
    int tid = threadIdx.x;
    const float* xb = x + ((size_t)b * 512 + c0) * 4096 + p0;
#pragma unroll
    for (int pass = 0; pass < 4; ++pass) {
        int cl = pass * 16 + (tid >> 4);
        int pq = (tid & 15) * 4;
        float4 v = *(const float4*)(xb + (size_t)cl * 4096 + pq);
        int c = c0 + cl, g = c >> 4;
        float mean = stats[(b * 32 + g) * 2], rstd = stats[(b * 32 + g) * 2 + 1];
        float sw = gw[c] * rstd;
        float sb = gb[c] - mean * sw;
        t[pq + 0][cl] = f2bs(v.x * sw + sb);
        t[pq + 1][cl] = f2bs(v.y * sw + sb);
        t[pq + 2][cl] = f2bs(v.z * sw + sb);
        t[pq + 3][cl] = f2bs(v.w * sw + sb);
    }
    __syncthreads();
    unsigned short* hb = ht + ((size_t)b * 4096 + p0) * 512 + c0;
#pragma unroll
    for (int pass = 0; pass < 2; ++pass) {
        int pl = pass * 32 + (tid >> 3);
        int c8 = (tid & 7) * 8;
        *(uint4*)(hb + (size_t)pl * 512 + c8) = *(const uint4*)&t[pl][c8];
    }
}

// ---------------- merged qkv NT GEMM (K=512, bf16): blocks 0..1023 = q|k, 1024..1535 = v ----------------
__global__ void gemm_qkv(const unsigned short* __restrict__ h_t, long long sP,
                         const unsigned short* __restrict__ wqkb,
                         const unsigned short* __restrict__ wvb,
                         char* __restrict__ q_i8, char* __restrict__ k_i8,
                         char* __restrict__ v_f8,
                         const float* __restrict__ biasqk, const float* __restrict__ vb,
                         float qs) {
    __shared__ __align__(16) unsigned short lA[128 * 64];
    __shared__ __align__(16) unsigned short lB[128 * 64];
    const int tid = threadIdx.x;
    const int wave = tid >> 6, lane = tid & 63;
    const int flat = blockIdx.x;
    const bool isqk = flat < 1024;
    int m0, n0, bz;
    const unsigned short *Ab, *Bb;
    if (isqk) {
        m0 = ((flat >> 3) & 31) * 128;
        n0 = (flat & 7) * 128;
        bz = flat >> 8;
        Ab = h_t + (size_t)bz * sP;
        Bb = wqkb;
    } else {
        const int g = flat - 1024;
        m0 = ((g >> 5) & 3) * 128;
        n0 = (g & 31) * 128;
        bz = g >> 7;
        Ab = wvb;
        Bb = h_t + (size_t)bz * sP;
    }

    floatx4 acc[4][4];
#pragma unroll
    for (int i = 0; i < 4; i++)
#pragma unroll
        for (int j = 0; j < 4; j++) acc[i][j] = (floatx4){0.f, 0.f, 0.f, 0.f};

    const int wm = (wave >> 1) * 64, wn = (wave & 1) * 64;
    const int quad = lane >> 4;
    const int lc = lane & 15;
    const int lc7 = lc & 7;

    for (int kt = 0; kt < 8; ++kt) {
        const int kbase = kt * 64;
#pragma unroll
        for (int c = 0; c < 4; ++c) {
            int d = c * 256 + tid;
            int r = d >> 3;
            int kc = (d & 7) ^ (r & 7);
            const unsigned short* ga = Ab + (size_t)(m0 + r) * 512 + kbase + kc * 8;
            const unsigned short* gb = Bb + (size_t)(n0 + r) * 512 + kbase + kc * 8;
            __builtin_amdgcn_global_load_lds(
                (const __attribute__((address_space(1))) void*)ga,
                (__attribute__((address_space(3))) void*)&lA[(size_t)(c * 256 + wave * 64) * 8], 16, 0, 0);
            __builtin_amdgcn_global_load_lds(
                (const __attribute__((address_space(1))) void*)gb,
                (__attribute__((address_space(3))) void*)&lB[(size_t)(c * 256 + wave * 64) * 8], 16, 0, 0);
        }
        __syncthreads();
#pragma unroll
        for (int kk = 0; kk < 2; ++kk) {
            const int swz = ((kk * 4 + quad) ^ lc7) * 8;
            short8 af[4], bf[4];
#pragma unroll
            for (int i = 0; i < 4; i++)
                af[i] = *(const short8*)&lA[(size_t)(wm + i * 16 + lc) * 64 + swz];
#pragma unroll
            for (int j = 0; j < 4; j++)
                bf[j] = *(const short8*)&lB[(size_t)(wn + j * 16 + lc) * 64 + swz];
#pragma unroll
            for (int i = 0; i < 4; i++)
#pragma unroll
                for (int j = 0; j < 4; j++)
                    acc[i][j] = __builtin_amdgcn_mfma_f32_16x16x32_bf16(af[i], bf[j], acc[i][j], 0, 0, 0);
        }
        __syncthreads();
    }

    const int rowb = quad * 4;
    if (isqk) {
#pragma unroll
        for (int i = 0; i < 4; i++) {
#pragma unroll
            for (int r = 0; r < 4; r++) {
                const int m = m0 + wm + i * 16 + rowb + r;
                float q[4];
#pragma unroll
                for (int j = 0; j < 4; j++) {
                    const int n = n0 + wn + j * 16 + lc;
                    q[j] = fminf(fmaxf((acc[i][j][r] + biasqk[n]) * qs, -127.f), 127.f);
                }
                const int col64 = n0 + wn;
                char* outp = (col64 < 512) ? q_i8 : k_i8;
                size_t idx = (size_t)bz * sP + (size_t)m * 512 +
                             (col64 - ((col64 < 512) ? 0 : 512)) + lc * 4;
                *(unsigned*)(outp + idx) = pack_i8x4(q[0], q[1], q[2], q[3]);
            }
        }
    } else {
#pragma unroll
        for (int i = 0; i < 4; i++) {
#pragma unroll
            for (int r = 0; r < 4; r++) {
                const int m = m0 + wm + i * 16 + rowb + r;
                const float bm = vb[m];
                float q[4];
#pragma unroll
                for (int j = 0; j < 4; j++)
                    q[j] = fminf(fmaxf(acc[i][j][r] + bm, -448.f), 448.f);
                size_t idx = (size_t)bz * sP + (size_t)m * 4096 + n0 + wn + lc * 4;
                *(unsigned*)(v_f8 + idx) = pack_fp8x4(q[0], q[1], q[2], q[3]);
            }
        }
    }
}

// ---------------- NT GEMM, bf16, fp32-out epilogue (proj): y = A.B^T/rowsum[n] + bias[m] + resid ----------------
__global__ void gemm_proj(const unsigned short* __restrict__ A,
                          const unsigned short* __restrict__ B, long long sBb,
                          float* __restrict__ Cv, long long sCb,
                          const float* __restrict__ bias,
                          const float* __restrict__ resid, long long sRb,
                          const float* __restrict__ rsum,
                          int M, int N, int K) {
    __shared__ __align__(16) unsigned short lA[128 * 64];
    __shared__ __align__(16) unsigned short lB[128 * 64];
    const int tid = threadIdx.x;
    const int wave = tid >> 6, lane = tid & 63;
    const int m0 = blockIdx.y * 128, n0 = blockIdx.x * 128, bz = blockIdx.z;
    const unsigned short* Ab = A;
    const unsigned short* Bb = B + (size_t)bz * sBb;

    floatx4 acc[4][4];
#pragma unroll
    for (int i = 0; i < 4; i++)
#pragma unroll
        for (int j = 0; j < 4; j++) acc[i][j] = (floatx4){0.f, 0.f, 0.f, 0.f};

    const int wm = (wave >> 1) * 64, wn = (wave & 1) * 64;
    const int quad = lane >> 4;
    const int lc = lane & 15;
    const int lc7 = lc & 7;

    const int nk = K >> 6;
    for (int kt = 0; kt < nk; ++kt) {
        const int kbase = kt * 64;
#pragma unroll
        for (int c = 0; c < 4; ++c) {
            int d = c * 256 + tid;
            int r = d >> 3;
            int kc = (d & 7) ^ (r & 7);
            const unsigned short* ga = Ab + (size_t)(m0 + r) * 512 + ((kbase & 511) + kc * 8);
            const unsigned short* gb = Bb + (size_t)(n0 + r) * 1024 + kbase + kc * 8;
            __builtin_amdgcn_global_load_lds(
                (const __attribute__((address_space(1))) void*)ga,
                (__attribute__((address_space(3))) void*)&lA[(size_t)(c * 256 + wave * 64) * 8], 16, 0, 0);
            __builtin_amdgcn_global_load_lds(
                (const __attribute__((address_space(1))) void*)gb,
                (__attribute__((address_space(3))) void*)&lB[(size_t)(c * 256 + wave * 64) * 8], 16, 0, 0);
        }
        __syncthreads();
#pragma unroll
        for (int kk = 0; kk < 2; ++kk) {
            const int swz = ((kk * 4 + quad) ^ lc7) * 8;
            short8 af[4], bf[4];
#pragma unroll
            for (int i = 0; i < 4; i++)
                af[i] = *(const short8*)&lA[(size_t)(wm + i * 16 + lc) * 64 + swz];
#pragma unroll
            for (int j = 0; j < 4; j++)
                bf[j] = *(const short8*)&lB[(size_t)(wn + j * 16 + lc) * 64 + swz];
#pragma unroll
            for (int i = 0; i < 4; i++)
#pragma unroll
                for (int j = 0; j < 4; j++)
                    acc[i][j] = __builtin_amdgcn_mfma_f32_16x16x32_bf16(af[i], bf[j], acc[i][j], 0, 0, 0);
        }
        __syncthreads();
    }

    float rsinv[4];
#pragma unroll
    for (int j = 0; j < 4; j++) {
        const int n = n0 + wn + j * 16 + lc;
        rsinv[j] = 1.f / (rsum[(size_t)bz * 4096 + n] + rsum[(size_t)(4 + bz) * 4096 + n]);
    }

    const int rowb = quad * 4;
#pragma unroll
    for (int i = 0; i < 4; i++) {
#pragma unroll
        for (int r = 0; r < 4; r++) {
            const int m = m0 + wm + i * 16 + rowb + r;
            const float bm = bias[m];
#pragma unroll
            for (int j = 0; j < 4; j++) {
                const int n = n0 + wn + j * 16 + lc;
                size_t idx = (size_t)bz * sCb + (size_t)m * N + n;
                Cv[idx] = acc[i][j][r] * rsinv[j] + bm + resid[(size_t)bz * sRb + (size_t)m * N + n];
            }
        }
    }
}

// ---------------- fused attention: S^T = K.Q^T (i8 16x16) -> exp -> P (LDS, fp8)
//                                   -> O_un += P.V^T (MX-scaled fp8 32x32x64, scale=1.0) ----------------
// Grid: 256 blocks = 8 xcd-groups (bz*2+split) x 32 q-tiles. 512 thr (8 waves). 1 block/CU.
// Ql[512 lines][128]: row = chq*128+q, slot = ((ch>>4)&7) ^ (q&7)   (unchanged)
// Kl[256 lines][128]: row = chq*64+kv, slot = ((ch>>4)&7) ^ (kv&7)  (unchanged)
// Vl/Pl: 2 rows per 128B line; row r chunk c (16B, kv-positions 16c..16c+15) at
//        slot = (((r&1)<<2)|c) ^ ((r>>1)&7). Per-8-lane slot-distinct for all reads/writes.
// Phase B lane fragment: rows r = base + (l&31), kv-chunks 2h,2h+1 (h=l>>5) -> v8i32, K=64.
__global__ __launch_bounds__(512, 2) void attn_fused(
    const char* __restrict__ Qg, const char* __restrict__ Kg,
    const char* __restrict__ Vg,
    unsigned short* __restrict__ Ou, long long sOb,
    float* __restrict__ rsum, float scale2) {
    __shared__ __align__(16) char Ql[512 * 128];
    __shared__ __align__(16) char Kl[256 * 128];
    __shared__ __align__(16) char Vl[256 * 128];
    __shared__ __align__(16) char Pl[64 * 128];
    const int tid = threadIdx.x;
    const int wave = tid >> 6, lane = tid & 63;
    const int quad = lane >> 4, lc = lane & 15;
    const int lc7 = lc & 7;
    const int l31 = lane & 31, lh = lane >> 5;
    const int id = blockIdx.x;
    const int xcd = id & 7, qi = id >> 3;
    const int bz = xcd >> 1, split = xcd & 1;
    const int q0 = qi * 128;
    const int kvbase = split * 2048;
    const int NIT = 32;

    const char* Qb = Qg + ((size_t)bz * 4096 + q0) * 512;
    const char* Kb = Kg + ((size_t)bz * 4096 + kvbase) * 512;
    const char* Vb = Vg + (size_t)bz * 2097152 + kvbase;

    const int wq = wave * 16;
    const int mO = (wave >> 2) * 64, nO = (wave & 3) * 128;

    // ---- staging (issue only; 16B/thread/call; LDS linear in thread order) ----
    auto stageQ = [&]() {
#pragma unroll
        for (int c = 0; c < 8; ++c) {
            int f = c * 512 + tid;
            int rr = f >> 3, cs = f & 7;
            int qq = rr & 127, chq = rr >> 7;
            int s = cs ^ (qq & 7);
            __builtin_amdgcn_global_load_lds(
                (const __attribute__((address_space(1))) void*)(Qb + (size_t)qq * 512 + chq * 128 + s * 16),
                (__attribute__((address_space(3))) void*)(Ql + (size_t)f * 16), 16, 0, 0);
        }
    };
    auto stageK = [&](int t) {
#pragma unroll
        for (int c = 0; c < 4; ++c) {
            int f = c * 512 + tid;
            int rr = f >> 3, cs = f & 7;
            int kv = rr & 63, chq = rr >> 6;
            int s = cs ^ (kv & 7);
            __builtin_amdgcn_global_load_lds(
                (const __attribute__((address_space(1))) void*)(Kb + (size_t)(t * 64 + kv) * 512 + chq * 128 + s * 16),
                (__attribute__((address_space(3))) void*)(Kl + (size_t)f * 16), 16, 0, 0);
        }
    };
    auto stageV = [&](int t) {
#pragma unroll
        for (int c = 0; c < 4; ++c) {
            int f = c * 512 + tid;
            int u = (f & 7) ^ ((f >> 3) & 7);
            int d = ((f >> 3) << 1) | (u >> 2);
            int gq = u & 3;
            __builtin_amdgcn_global_load_lds(
                (const __attribute__((address_space(1))) void*)(Vb + (size_t)d * 4096 + t * 64 + gq * 16),
                (__attribute__((address_space(3))) void*)(Vl + (size_t)f * 16), 16, 0, 0);
        }
    };

    floatx16 acco[2][4];
#pragma unroll
    for (int i = 0; i < 2; ++i)
#pragma unroll
        for (int j = 0; j < 4; ++j)
#pragma unroll
            for (int r = 0; r < 16; ++r) acco[i][j][r] = 0.f;
    float rs = 0.f;

    stageQ();
    stageK(0);
    stageV(0);
    syncfull();

    const int q = wq + lc;       // this lane's q-column in S^T
    const int q7 = q & 7;

    for (int t = 0; t < NIT; ++t) {
        // ---- phase A: S^T[kv=64][q=128] = K . Q^T over ch=512, then exp->P ----
        if (t > 0) stageV(t);  // Vl free since barrier-B(t-1); landed by end-of-A waitcnt
        i32x4 accs[4];
#pragma unroll
        for (int ki = 0; ki < 4; ++ki) accs[ki] = (i32x4){0, 0, 0, 0};
#pragma unroll
        for (int ks = 0; ks < 8; ++ks) {
            const int g = ks * 4 + quad;
            const int gh = g >> 3, gl = g & 7;
            i32x4 bfrag = *(const i32x4*)&Ql[(size_t)(gh * 128 + q) * 128 + ((gl ^ q7) << 4)];
#pragma unroll
            for (int ki = 0; ki < 4; ++ki) {
                const int ar = ki * 16 + lc;
                i32x4 afrag = *(const i32x4*)&Kl[(size_t)(gh * 64 + ar) * 128 + ((gl ^ lc7) << 4)];
                accs[ki] = __builtin_amdgcn_mfma_i32_16x16x64_i8(afrag, bfrag, accs[ki], 0, 0, 0);
            }
        }
        float e[4][4];
#pragma unroll
        for (int ki = 0; ki < 4; ++ki)
#pragma unroll
            for (int r = 0; r < 4; ++r) {
                e[ki][r] = fminf(exp2f(fmaf((float)accs[ki][r], scale2, -2.0f)), 448.f);
                rs += e[ki][r];
            }
        // P row q, chunk quad = positions quad*16..+15 (word r at +r*4, byte ki): one b128/lane
        {
            unsigned w0 = pack_fp8x4(e[0][0], e[1][0], e[2][0], e[3][0]);
            unsigned w1 = pack_fp8x4(e[0][1], e[1][1], e[2][1], e[3][1]);
            unsigned w2 = pack_fp8x4(e[0][2], e[1][2], e[2][2], e[3][2]);
            unsigned w3 = pack_fp8x4(e[0][3], e[1][3], e[2][3], e[3][3]);
            const int L = q >> 1;
            const int sl = ((((q & 1) << 2) | quad) ^ (L & 7));
            *(i32x4*)&Pl[(size_t)L * 128 + (sl << 4)] = (i32x4){(int)w0, (int)w1, (int)w2, (int)w3};
        }
        syncfull();  // P visible; V(t) landed; all waves done reading Kl(t)

        // ---- phase B: O += P . V^T via MX-scaled fp8 MFMA (K=64, scales = 1.0) ----
        if (t + 1 < NIT) stageK(t + 1);  // Kl free; landed by end-of-B waitcnt
        {
            i32x8 pa[2], vv[4];
#pragma unroll
            for (int i = 0; i < 2; ++i) {
                const int r_ = mO + i * 32 + l31;
                const int L = r_ >> 1;
                const int sb = ((r_ & 1) << 2) | (lh << 1);
                i32x4 lo = *(const i32x4*)&Pl[(size_t)L * 128 + ((sb ^ (L & 7)) << 4)];
                i32x4 hi = *(const i32x4*)&Pl[(size_t)L * 128 + (((sb | 1) ^ (L & 7)) << 4)];
                pa[i] = __builtin_shufflevector(lo, hi, 0, 1, 2, 3, 4, 5, 6, 7);
            }
#pragma unroll
            for (int j = 0; j < 4; ++j) {
                const int r_ = nO + j * 32 + l31;
                const int L = r_ >> 1;
                const int sb = ((r_ & 1) << 2) | (lh << 1);
                i32x4 lo = *(const i32x4*)&Vl[(size_t)L * 128 + ((sb ^ (L & 7)) << 4)];
                i32x4 hi = *(const i32x4*)&Vl[(size_t)L * 128 + (((sb | 1) ^ (L & 7)) << 4)];
                vv[j] = __builtin_shufflevector(lo, hi, 0, 1, 2, 3, 4, 5, 6, 7);
            }
#pragma unroll
            for (int i = 0; i < 2; ++i)
#pragma unroll
                for (int j = 0; j < 4; ++j)
                    acco[i][j] = __builtin_amdgcn_mfma_scale_f32_32x32x64_f8f6f4(
                        pa[i], vv[j], acco[i][j], 0, 0,
                        0, 0x7f7f7f7f, 0, 0x7f7f7f7f);
        }
        syncfull();  // K(t+1) landed; all waves done reading Vl(t), Pl(t)
    }

    // ---- epilogue: rowsum partial (this kv-half) + unnormalized O store (bf16, perm-d) ----
    rs += __shfl_xor(rs, 16);
    rs += __shfl_xor(rs, 32);
    if (quad == 0) rsum[((size_t)(split * 4 + bz)) * 4096 + q0 + q] = rs;

    // 32x32 C/D: col d = nO + j*32 + l31, row q = mO + i*32 + (reg&3) + 8*(reg>>2) + 4*lh
    // store perm (per 64-block): element j*32+l31 -> position l31*2 + (j&1); wpb matches.
#pragma unroll
    for (int i = 0; i < 2; ++i) {
#pragma unroll
        for (int reg = 0; reg < 16; ++reg) {
            const int m = q0 + mO + i * 32 + (reg & 3) + 8 * (reg >> 2) + 4 * lh;
            unsigned u01 = (unsigned)f2bs(acco[i][0][reg]) | ((unsigned)f2bs(acco[i][1][reg]) << 16);
            unsigned u23 = (unsigned)f2bs(acco[i][2][reg]) | ((unsigned)f2bs(acco[i][3][reg]) << 16);
            unsigned short* base = Ou + (size_t)bz * sOb + (size_t)m * 1024 + split * 512 + nO;
            *(unsigned*)(base + l31 * 2) = u01;
            *(unsigned*)(base + 64 + l31 * 2) = u23;
        }
    }
}

extern "C" void kernel_launch(void* const* d_in, const int* in_sizes, int n_in,
                              void* d_out, int out_size, void* d_ws, size_t ws_size,
                              hipStream_t stream) {
    (void)in_sizes; (void)n_in; (void)out_size; (void)ws_size;
    const float* x   = (const float*)d_in[0];
    const float* gnw = (const float*)d_in[1];
    const float* gnb = (const float*)d_in[2];
    const float* qw  = (const float*)d_in[3];
    const float* qb  = (const float*)d_in[4];
    const float* kw  = (const float*)d_in[5];
    const float* kb  = (const float*)d_in[6];
    const float* vw  = (const float*)d_in[7];
    const float* vb  = (const float*)d_in[8];
    const float* pw  = (const float*)d_in[9];
    const float* pb  = (const float*)d_in[10];
    float* out = (float*)d_out;

    char* ws = (char*)d_ws;
    unsigned short* h_t = (unsigned short*)(ws);
    char* q_i8 = (char*)(ws + (16ull << 20));
    char* k_i8 = (char*)(ws + (32ull << 20));
    char* v_f8 = (char*)(ws + (48ull << 20));
    unsigned short* wqkb = (unsigned short*)(ws + (64ull << 20));  // [qw;kw] 1024x512
    unsigned short* wvb = (unsigned short*)(ws + (65ull << 20));
    unsigned short* wpb = wvb + 262144;  // o-perm k-cols
    float* stats  = (float*)(ws + (66ull << 20));
    float* biasqk = (float*)(ws + (66ull << 20) + 8192);
    float* rowsum = (float*)(ws + (66ull << 20) + 65536);          // [2 splits][4 bz][4096] f32
    unsigned short* o_un = (unsigned short*)(ws + (72ull << 20));  // [4 bz][4096 q][1024] bf16

    const long long sP  = 2097152;   // 4096*512 elements per batch
    const long long sOb = 4194304;   // 4096*1024 elements per batch (o_un)
    const float QS = 16.f;
    const float SC = 0.044194173824159216f / (QS * QS);
    const float LOG2E = 1.4426950408889634f;

    // setup + gn_stats merged
    pre_kernel<<<1153, 256, 0, stream>>>(x, qw, kw, vw, pw, qb, kb, wqkb, wvb, wpb,
                                         biasqk, stats);
    gn_apply_kernel<<<dim3(64, 8, 4), 256, 0, stream>>>(x, stats, gnw, gnb, h_t);
    // merged q|k (1024 blocks) + v (512 blocks)
    gemm_qkv<<<1536, 256, 0, stream>>>(h_t, sP, wqkb, wvb, q_i8, k_i8, v_f8, biasqk, vb, QS);
    // fused S^T->exp->P(LDS)->O_un, kv-split x2, rowsum partials; PV via MX-scaled fp8
    attn_fused<<<dim3(256), 512, 0, stream>>>(q_i8, k_i8, v_f8, o_un, sOb, rowsum,
                                              SC * LOG2E);
    // y = x + wp~ . [O0;O1]^T / rowsum + pb: M=512(o), N=4096(p), K=1024
    gemm_proj<<<dim3(32, 4, 4), 256, 0, stream>>>(wpb, o_un, sOb, out, sP, pb, x, sP,
                                                  rowsum, 512, 4096, 1024);
}